// Round 5
// baseline (401.552 us; speedup 1.0000x reference)
//
#include <hip/hip_runtime.h>
#include <hip/hip_bf16.h>
#include <math.h>

#define BS_ 8
#define B_  4
#define M_  2048
#define D_  128
#define N_  1024
#define NEG (-1e30f)

typedef unsigned short us_t;
typedef __attribute__((ext_vector_type(8))) short bf8v;   // 8 bf16 (A/B frag)
typedef __attribute__((ext_vector_type(4))) float f4v;    // C/D frag

__device__ __forceinline__ float softplus_(float x) {
    return (x > 20.0f) ? x : log1pf(expf(x));
}
__device__ __forceinline__ float dot4_acc(float4 a, float4 b, float acc) {
    acc = fmaf(a.x, b.x, acc);
    acc = fmaf(a.y, b.y, acc);
    acc = fmaf(a.z, b.z, acc);
    acc = fmaf(a.w, b.w, acc);
    return acc;
}
__device__ __forceinline__ us_t f2bf(float x) {
    __hip_bfloat16 h = __float2bfloat16(x);   // RNE
    return __builtin_bit_cast(us_t, h);
}
__device__ __forceinline__ float bf2f(us_t u) {
    unsigned v = ((unsigned)u) << 16;
    return __builtin_bit_cast(float, v);
}
__device__ __forceinline__ bf8v gfrag(const us_t* p) { return *(const bf8v*)p; }  // 16B L2 load
// LDS swizzle: XOR bits 3-5 of ushort index with row&7
__device__ __forceinline__ int swz(int us_idx, int row) { return us_idx ^ ((row & 7) << 3); }

// ---------------------------------------------------------------------------
// conv_k: f32 -> bf16 conversions into ws (unchanged, known-good).
// ---------------------------------------------------------------------------
__global__ __launch_bounds__(256, 2) void conv_k(
    const float* __restrict__ w_cand, const float* __restrict__ emK,
    const float* __restrict__ emV, const int* __restrict__ bp,
    us_t* __restrict__ Kbf, us_t* __restrict__ Wcg,
    us_t* __restrict__ WcTg, us_t* __restrict__ Vtg, float* __restrict__ invnW)
{
    __shared__ float wt[64][132];
    __shared__ float invn[64];
    const int tid = threadIdx.x;
    const int bs  = blockIdx.y;
    const int bx  = blockIdx.x;
    const int b   = bp[0];

    if (bx < 32) {
        const float* src = emK + ((size_t)(bs * B_ + b)) * M_ * D_ + (size_t)bx * 64 * D_;
        us_t* dst = Kbf + (size_t)bs * M_ * D_ + (size_t)bx * 64 * D_;
        for (int i = tid; i < 64 * 128 / 4; i += 256) {
            float4 v = ((const float4*)src)[i];
            ushort4 o;
            o.x = f2bf(v.x); o.y = f2bf(v.y); o.z = f2bf(v.z); o.w = f2bf(v.w);
            ((ushort4*)dst)[i] = o;
        }
        return;
    }
    if (bx >= 48) {
        const int m0 = (bx - 48) * 64;
        const float* Vb = emV + ((size_t)(bs * B_ + b)) * M_ * D_ + (size_t)m0 * D_;
        for (int c = tid; c < 64 * 32; c += 256) {
            int row = c >> 5, col = (c & 31) << 2;
            *(float4*)&wt[row][col] = *(const float4*)&Vb[row * D_ + col];
        }
        __syncthreads();
        us_t* VtB = Vtg + (size_t)bs * D_ * M_;
        for (int c = tid; c < 1024; c += 256) {
            int d = c >> 3, mc = c & 7;
            uint4 o;
            o.x = (unsigned)f2bf(wt[mc * 8 + 0][d]) | ((unsigned)f2bf(wt[mc * 8 + 1][d]) << 16);
            o.y = (unsigned)f2bf(wt[mc * 8 + 2][d]) | ((unsigned)f2bf(wt[mc * 8 + 3][d]) << 16);
            o.z = (unsigned)f2bf(wt[mc * 8 + 4][d]) | ((unsigned)f2bf(wt[mc * 8 + 5][d]) << 16);
            o.w = (unsigned)f2bf(wt[mc * 8 + 6][d]) | ((unsigned)f2bf(wt[mc * 8 + 7][d]) << 16);
            *(uint4*)&VtB[(size_t)d * M_ + m0 + mc * 8] = o;
        }
        return;
    }
    const int n0 = (bx - 32) * 64;
    const float* Wb = w_cand + (size_t)bs * N_ * D_ + (size_t)n0 * D_;
    for (int c = tid; c < 64 * 32; c += 256) {
        int row = c >> 5, col = (c & 31) << 2;
        *(float4*)&wt[row][col] = *(const float4*)&Wb[row * D_ + col];
    }
    __syncthreads();
    {
        int r = tid >> 2, j = tid & 3;
        float ss = 0.0f;
        #pragma unroll
        for (int q = 0; q < 8; ++q) {
            float4 v = *(float4*)&wt[r][q * 16 + j * 4];
            ss = dot4_acc(v, v, ss);
        }
        ss += __shfl_xor(ss, 1, 4);
        ss += __shfl_xor(ss, 2, 4);
        if (j == 0) invn[r] = 1.0f / fmaxf(sqrtf(ss), 1e-12f);
    }
    __syncthreads();
    us_t* WcB = Wcg + (size_t)bs * N_ * D_ + (size_t)n0 * D_;
    for (int e = tid; e < 8192; e += 256) {
        int row = e >> 7, col = e & 127;
        WcB[row * D_ + col] = f2bf(wt[row][col]);
    }
    us_t* WcTB = WcTg + (size_t)bs * D_ * N_;
    for (int e = tid; e < 8192; e += 256) {
        int d = e >> 6, n = e & 63;
        WcTB[d * N_ + n0 + n] = f2bf(wt[n][d]);
    }
    if (tid < 64) invnW[(size_t)bs * N_ + n0 + tid] = invn[tid];
}

// ---------------------------------------------------------------------------
// attn_part_k: flash partial over one M-quarter. Barrier-free, L2-direct
// fragments. 512 blocks, 4 indep waves (wave = 16 n-rows).
// ---------------------------------------------------------------------------
__global__ __launch_bounds__(256, 2) void attn_part_k(
    const float* __restrict__ ySrc, const us_t* __restrict__ Kbf,
    const us_t* __restrict__ Vtg, const float* __restrict__ emS,
    const float* __restrict__ raw_tau, const int* __restrict__ bp,
    us_t* __restrict__ pDelta, float2* __restrict__ pML)
{
    __shared__ us_t Pl[4][1024];     // wave-private P tiles [16n][64m]

    const int tid = threadIdx.x;
    const int raw = blockIdx.x;
    const int logical = (raw & 7) * 64 + (raw >> 3);   // 512 = 8 XCD * 64
    const int bs = logical >> 6;
    const int rem = logical & 63;
    const int nt = rem >> 2;
    const int q  = rem & 3;
    const int b = bp[0];
    const float rtau = 1.0f / (softplus_(raw_tau[b]) + 0.1f);

    const us_t* KbB = Kbf + (size_t)bs * M_ * D_ + (size_t)(q * 512) * D_;
    const us_t* VtB = Vtg + (size_t)bs * D_ * M_;
    const float* SbB = emS + ((size_t)(bs * B_ + b)) * M_ + q * 512;

    const int wave = tid >> 6, lane = tid & 63;
    const int r = lane & 15, kg = lane >> 4;
    us_t* Pw = Pl[wave];

    // y fragments (bf16) straight from global f32
    bf8v yb[4];
    {
        const float* yrow = ySrc + ((size_t)bs * N_ + nt * 64 + wave * 16 + r) * D_;
        #pragma unroll
        for (int kk = 0; kk < 4; ++kk) {
            float4 a = *(const float4*)&yrow[kk * 32 + kg * 8];
            float4 c = *(const float4*)&yrow[kk * 32 + kg * 8 + 4];
            bf8v t;
            t[0] = (short)f2bf(a.x); t[1] = (short)f2bf(a.y);
            t[2] = (short)f2bf(a.z); t[3] = (short)f2bf(a.w);
            t[4] = (short)f2bf(c.x); t[5] = (short)f2bf(c.y);
            t[6] = (short)f2bf(c.z); t[7] = (short)f2bf(c.w);
            yb[kk] = t;
        }
    }

    f4v cD[8];
    #pragma unroll
    for (int df = 0; df < 8; ++df) cD[df] = (f4v){0.f, 0.f, 0.f, 0.f};
    float mrun = NEG, lsum = 0.0f;

    for (int t = 0; t < 8; ++t) {
        // scores via L2-direct K fragments
        float sv[4][4];
        #pragma unroll
        for (int mf = 0; mf < 4; ++mf) {
            f4v c4 = {0.f, 0.f, 0.f, 0.f};
            #pragma unroll
            for (int kk = 0; kk < 4; ++kk) {
                bf8v a = gfrag(&KbB[(size_t)(t * 64 + mf * 16 + r) * D_ + kk * 32 + kg * 8]);
                c4 = __builtin_amdgcn_mfma_f32_16x16x32_bf16(a, yb[kk], c4, 0, 0, 0);
            }
            #pragma unroll
            for (int reg = 0; reg < 4; ++reg) {
                float sb = SbB[t * 64 + mf * 16 + kg * 4 + reg];
                sv[mf][reg] = (sb > 0.0f) ? c4[reg] * rtau : NEG;
            }
        }
        float tmax = NEG;
        #pragma unroll
        for (int mf = 0; mf < 4; ++mf)
            #pragma unroll
            for (int reg = 0; reg < 4; ++reg) tmax = fmaxf(tmax, sv[mf][reg]);
        tmax = fmaxf(tmax, __shfl_xor(tmax, 16, 64));
        tmax = fmaxf(tmax, __shfl_xor(tmax, 32, 64));
        float mnew = fmaxf(mrun, tmax);
        float f = (mnew > -1e29f) ? __expf(mrun - mnew) : 1.0f;
        mrun = mnew;

        float psum = 0.0f;
        #pragma unroll
        for (int mf = 0; mf < 4; ++mf)
            #pragma unroll
            for (int reg = 0; reg < 4; ++reg) {
                float p = (sv[mf][reg] > -1e29f) ? __expf(sv[mf][reg] - mnew) : 0.0f;
                psum += p;
                int ml = mf * 16 + kg * 4 + reg;
                Pw[swz(r * 64 + ml, r)] = f2bf(p);
            }
        lsum = lsum * f + psum;

        float fr[4];
        #pragma unroll
        for (int reg = 0; reg < 4; ++reg) fr[reg] = __shfl(f, kg * 4 + reg, 64);
        #pragma unroll
        for (int df = 0; df < 8; ++df)
            #pragma unroll
            for (int reg = 0; reg < 4; ++reg) cD[df][reg] *= fr[reg];

        // PV via L2-direct Vt fragments
        #pragma unroll
        for (int kk = 0; kk < 2; ++kk) {
            bf8v pa = *(bf8v*)&Pw[swz(r * 64 + kk * 32 + kg * 8, r)];
            #pragma unroll
            for (int df = 0; df < 8; ++df) {
                bf8v bv = gfrag(&VtB[(size_t)(df * 16 + r) * M_ + q * 512 + t * 64 + kk * 32 + kg * 8]);
                cD[df] = __builtin_amdgcn_mfma_f32_16x16x32_bf16(pa, bv, cD[df], 0, 0, 0);
            }
        }
    }

    lsum += __shfl_xor(lsum, 16, 64);
    lsum += __shfl_xor(lsum, 32, 64);
    float invl = (lsum > 0.0f) ? 1.0f / lsum : 0.0f;

    us_t* pd = pDelta + ((size_t)((bs * 16 + nt) * 4 + q)) * (64 * 128);
    #pragma unroll
    for (int reg = 0; reg < 4; ++reg) {
        float il = __shfl(invl, kg * 4 + reg, 64);
        int nrow = wave * 16 + kg * 4 + reg;
        #pragma unroll
        for (int df = 0; df < 8; ++df)
            pd[nrow * 128 + df * 16 + r] = f2bf(cD[df][reg] * il);
    }
    if (kg == 0) {
        int nrow = wave * 16 + r;
        pML[((size_t)((bs * 16 + nt) * 4 + q)) * 64 + nrow] = make_float2(mrun, lsum);
    }
}

// ---------------------------------------------------------------------------
// attn_merge_k: merge 4 quarters, gate, update y (unchanged).
// ---------------------------------------------------------------------------
__global__ __launch_bounds__(256, 2) void attn_merge_k(
    const float* __restrict__ ySrc, const float* __restrict__ seed,
    const us_t* __restrict__ pDelta, const float2* __restrict__ pML,
    const float* __restrict__ w1, const float* __restrict__ w2,
    const float* __restrict__ gb, const int* __restrict__ bp,
    float* __restrict__ yOut, int mode)
{
    __shared__ float w1L[128], w2L[128], gbL[128];
    const int tid = threadIdx.x, raw = blockIdx.x;
    const int logical = (raw & 7) * 16 + (raw >> 3);
    const int bs = logical >> 4, nt = logical & 15;
    const int b = bp[0];
    if (tid < 128) {
        w1L[tid] = w1[b * D_ + tid];
        w2L[tid] = w2[b * D_ + tid];
        gbL[tid] = gb[b * D_ + tid];
    }
    __syncthreads();
    const int rw = tid >> 2, dj = tid & 3;
    const size_t base = ((size_t)(bs * 16 + nt)) * 4;
    float2 ml0 = pML[(base + 0) * 64 + rw];
    float2 ml1 = pML[(base + 1) * 64 + rw];
    float2 ml2 = pML[(base + 2) * 64 + rw];
    float2 ml3 = pML[(base + 3) * 64 + rw];
    float M = fmaxf(fmaxf(ml0.x, ml1.x), fmaxf(ml2.x, ml3.x));
    float w0 = 0.f, wA = 0.f, wB = 0.f, w3 = 0.f, tot = 0.f;
    if (M > -1e29f) {
        w0 = ml0.y * __expf(ml0.x - M);
        wA = ml1.y * __expf(ml1.x - M);
        wB = ml2.y * __expf(ml2.x - M);
        w3 = ml3.y * __expf(ml3.x - M);
        tot = w0 + wA + wB + w3;
    }
    float inv = (tot > 0.0f) ? 1.0f / tot : 0.0f;
    w0 *= inv; wA *= inv; wB *= inv; w3 *= inv;

    const us_t* pd0 = pDelta + (base + 0) * 8192 + rw * 128;
    const us_t* pd1 = pDelta + (base + 1) * 8192 + rw * 128;
    const us_t* pd2 = pDelta + (base + 2) * 8192 + rw * 128;
    const us_t* pd3 = pDelta + (base + 3) * 8192 + rw * 128;
    const float* yrow = ySrc + ((size_t)bs * N_ + nt * 64 + rw) * D_;
    const float* srow = seed + ((size_t)bs * N_ + nt * 64 + rw) * D_;
    float* orow = yOut + ((size_t)bs * N_ + nt * 64 + rw) * D_;

    #pragma unroll
    for (int e = 0; e < 4; ++e) {
        int d0 = dj * 32 + e * 8;
        uint4 u0 = *(const uint4*)&pd0[d0];
        uint4 u1 = *(const uint4*)&pd1[d0];
        uint4 u2 = *(const uint4*)&pd2[d0];
        uint4 u3 = *(const uint4*)&pd3[d0];
        const us_t* a0 = (const us_t*)&u0;
        const us_t* a1 = (const us_t*)&u1;
        const us_t* a2 = (const us_t*)&u2;
        const us_t* a3 = (const us_t*)&u3;
        float4 ya = *(const float4*)&yrow[d0];
        float4 yc = *(const float4*)&yrow[d0 + 4];
        float yv[8] = {ya.x, ya.y, ya.z, ya.w, yc.x, yc.y, yc.z, yc.w};
        float res[8];
        #pragma unroll
        for (int j = 0; j < 8; ++j) {
            float dl = w0 * bf2f(a0[j]) + wA * bf2f(a1[j]) + wB * bf2f(a2[j]) + w3 * bf2f(a3[j]);
            int d = d0 + j;
            float g = 1.0f / (1.0f + __expf(-(w1L[d] * yv[j] + w2L[d] * dl + gbL[d])));
            res[j] = yv[j] + g * dl;
        }
        if (mode == 1) {
            float4 sa = *(const float4*)&srow[d0];
            float4 sc = *(const float4*)&srow[d0 + 4];
            res[0] -= sa.x; res[1] -= sa.y; res[2] -= sa.z; res[3] -= sa.w;
            res[4] -= sc.x; res[5] -= sc.y; res[6] -= sc.z; res[7] -= sc.w;
        }
        float4 o1; o1.x = res[0]; o1.y = res[1]; o1.z = res[2]; o1.w = res[3];
        float4 o2; o2.x = res[4]; o2.y = res[5]; o2.z = res[6]; o2.w = res[7];
        *(float4*)&orow[d0] = o1;
        *(float4*)&orow[d0 + 4] = o2;
    }
}

// ---------------------------------------------------------------------------
// stats_k: routing score stats over one M-quarter. Barrier-free, no LDS,
// L2-direct K fragments. 512 blocks, 4 indep waves.
// ---------------------------------------------------------------------------
__global__ __launch_bounds__(256, 2) void stats_k(
    const us_t* __restrict__ Wcg, const us_t* __restrict__ Kbf,
    const float* __restrict__ invnW, const float* __restrict__ emS,
    const float* __restrict__ raw_tau_w, const int* __restrict__ bp,
    float* __restrict__ mxW, float* __restrict__ smW)
{
    const int tid = threadIdx.x;
    const int raw = blockIdx.x;
    const int logical = (raw & 7) * 64 + (raw >> 3);
    const int bs = logical >> 6;
    const int rem = logical & 63;
    const int nt = rem >> 2;
    const int q  = rem & 3;
    const int b = bp[0];
    const float rtw = 1.0f / (softplus_(raw_tau_w[b]) + 0.1f);

    const us_t* KbB = Kbf + (size_t)bs * M_ * D_ + (size_t)(q * 512) * D_;
    const float* SbB = emS + ((size_t)(bs * B_ + b)) * M_ + q * 512;

    const int wave = tid >> 6, lane = tid & 63;
    const int r = lane & 15, kg = lane >> 4;
    const int n = nt * 64 + wave * 16 + r;

    bf8v wb[4];
    {
        const us_t* wrow = Wcg + ((size_t)bs * N_ + n) * D_;
        #pragma unroll
        for (int kk = 0; kk < 4; ++kk)
            wb[kk] = gfrag(&wrow[kk * 32 + kg * 8]);
    }
    const float ivn = invnW[(size_t)bs * N_ + n];

    float mx = NEG, sm = 0.0f;

    for (int t = 0; t < 8; ++t) {
        #pragma unroll
        for (int mf = 0; mf < 4; ++mf) {
            f4v c4 = {0.f, 0.f, 0.f, 0.f};
            #pragma unroll
            for (int kk = 0; kk < 4; ++kk) {
                bf8v a = gfrag(&KbB[(size_t)(t * 64 + mf * 16 + r) * D_ + kk * 32 + kg * 8]);
                c4 = __builtin_amdgcn_mfma_f32_16x16x32_bf16(a, wb[kk], c4, 0, 0, 0);
            }
            float v[4]; bool act[4];
            float lm = NEG;
            #pragma unroll
            for (int reg = 0; reg < 4; ++reg) {
                float sb = SbB[t * 64 + mf * 16 + kg * 4 + reg];
                v[reg] = c4[reg] * ivn * rtw;
                act[reg] = (sb > 0.0f);
                if (act[reg]) lm = fmaxf(lm, v[reg]);
            }
            float mnew = fmaxf(mx, lm);
            if (mnew > -1e29f) {
                float acc = sm * __expf(mx - mnew);
                #pragma unroll
                for (int reg = 0; reg < 4; ++reg)
                    if (act[reg]) acc += __expf(v[reg] - mnew);
                sm = acc; mx = mnew;
            }
        }
    }
    #pragma unroll
    for (int off = 16; off <= 32; off <<= 1) {
        float omx = __shfl_xor(mx, off, 64);
        float osm = __shfl_xor(sm, off, 64);
        float nm = fmaxf(mx, omx);
        if (nm > -1e29f) sm = sm * __expf(mx - nm) + osm * __expf(omx - nm);
        else sm = 0.0f;
        mx = nm;
    }
    if (kg == 0) {
        mxW[(size_t)(q * BS_ + bs) * N_ + n] = mx;
        smW[(size_t)(q * BS_ + bs) * N_ + n] = sm;
    }
}

// ---------------------------------------------------------------------------
// stats_fin_k: merge 4 quarters -> packed per-n constants (mx, riv, pun, invn).
// ---------------------------------------------------------------------------
__global__ __launch_bounds__(256) void stats_fin_k(
    const float* __restrict__ mxW, const float* __restrict__ smW,
    const float* __restrict__ novelty, const float* __restrict__ invnW,
    float4* __restrict__ cnsG)
{
    int idx = blockIdx.x * 256 + threadIdx.x;   // 32 blocks * 256 = 8192
    float m[4], s[4];
    #pragma unroll
    for (int q = 0; q < 4; ++q) {
        m[q] = mxW[q * (BS_ * N_) + idx];
        s[q] = smW[q * (BS_ * N_) + idx];
    }
    float MX = fmaxf(fmaxf(m[0], m[1]), fmaxf(m[2], m[3]));
    float SM = 0.0f;
    if (MX > -1e29f) {
        #pragma unroll
        for (int q = 0; q < 4; ++q)
            if (m[q] > -1e29f) SM += s[q] * __expf(m[q] - MX);
    }
    float nov = novelty[idx];
    float4 o;
    if (SM > 0.0f) { o.x = MX; o.y = nov / SM; o.z = -1.0f; }
    else           { o.x = 0.0f; o.y = 0.0f; o.z = nov * (1.0f / (float)M_); }
    o.w = invnW[idx];
    cnsG[idx] = o;
}

// ---------------------------------------------------------------------------
// update3_k: N-split update. 512 blocks x 4 waves = (2 m-subtiles x 2 n-halves).
// Barrier-free main loop (L2-direct W fragments, wave-private P tiles);
// one barrier to merge the two n-halves.
// ---------------------------------------------------------------------------
__global__ __launch_bounds__(256) void update3_k(
    const us_t* __restrict__ Kbf, const us_t* __restrict__ Wcg,
    const us_t* __restrict__ WcTg, const float* __restrict__ g_em,
    const float* __restrict__ emK, const float* __restrict__ emV,
    const float* __restrict__ emS, const float* __restrict__ emAge,
    const float* __restrict__ raw_tau_w, const int* __restrict__ bp,
    const float4* __restrict__ cnsG,
    float* __restrict__ outK, float* __restrict__ outV,
    float* __restrict__ outS, float* __restrict__ outA)
{
    __shared__ us_t Pl[4][1024];      // wave-private P [16m][64n]
    __shared__ us_t P2l[4][1024];
    __shared__ f4v partK[2][8][64];   // nh=1 partials [mf][df][lane]
    __shared__ f4v partV[2][8][64];
    __shared__ float4 partCs[2][64];

    const int tid = threadIdx.x;
    const int raw = blockIdx.x;
    const int logical = (raw & 7) * 64 + (raw >> 3);    // 512 = 8 XCD * 64
    const int bs = logical >> 6;
    const int m0 = (logical & 63) * 32;
    const int b = bp[0];
    const float rtw = 1.0f / (softplus_(raw_tau_w[b]) + 0.1f);
    const float ge = g_em[bs];

    const int wave = tid >> 6, lane = tid & 63;
    const int mf = wave & 1, nh = wave >> 1;
    const int r = lane & 15, kg = lane >> 4;
    const int mrow0 = m0 + mf * 16;

    const us_t* WcB  = Wcg + (size_t)bs * N_ * D_;
    const us_t* WcTB = WcTg + (size_t)bs * D_ * N_;
    const float4* cnsB = cnsG + (size_t)bs * N_;
    const float* SbRow = emS + ((size_t)(bs * B_ + b)) * M_ + mrow0;

    // A fragments (K rows), loaded once from L2
    bf8v a_s[4];
    {
        const us_t* arow = Kbf + ((size_t)bs * M_ + mrow0 + r) * D_;
        #pragma unroll
        for (int kk = 0; kk < 4; ++kk)
            a_s[kk] = gfrag(&arow[kk * 32 + kg * 8]);
    }
    bool act4[4];
    #pragma unroll
    for (int reg = 0; reg < 4; ++reg) act4[reg] = (SbRow[kg * 4 + reg] > 0.0f);

    f4v cK[8], cV[8];
    #pragma unroll
    for (int df = 0; df < 8; ++df) { cK[df] = (f4v){0,0,0,0}; cV[df] = (f4v){0,0,0,0}; }
    float csp[4] = {0.f, 0.f, 0.f, 0.f};

    us_t* Pw = Pl[wave];
    us_t* P2w = P2l[wave];

    for (int it = 0; it < 8; ++it) {
        const int n0 = (nh * 8 + it) * 64;
        // scores + P/P2 (wave-private)
        #pragma unroll
        for (int nf = 0; nf < 4; ++nf) {
            f4v c = {0.f, 0.f, 0.f, 0.f};
            #pragma unroll
            for (int kk = 0; kk < 4; ++kk) {
                bf8v bb = gfrag(&WcB[(size_t)(n0 + nf * 16 + r) * D_ + kk * 32 + kg * 8]);
                c = __builtin_amdgcn_mfma_f32_16x16x32_bf16(a_s[kk], bb, c, 0, 0, 0);
            }
            float4 cn = cnsB[n0 + nf * 16 + r];
            #pragma unroll
            for (int reg = 0; reg < 4; ++reg) {
                float p;
                if (cn.z >= 0.0f) p = cn.z;
                else p = act4[reg] ? cn.y * __expf(c[reg] * cn.w * rtw - cn.x) : 0.0f;
                csp[reg] += p;
                int mr = kg * 4 + reg;
                Pw[swz(mr * 64 + nf * 16 + r, mr)] = f2bf(p);
                P2w[swz(mr * 64 + nf * 16 + r, mr)] = f2bf(p * cn.w);
            }
        }
        // update GEMMs (B frags from L2)
        #pragma unroll
        for (int kk2 = 0; kk2 < 2; ++kk2) {
            bf8v pa  = *(bf8v*)&Pw[swz(r * 64 + kk2 * 32 + kg * 8, r)];
            bf8v pa2 = *(bf8v*)&P2w[swz(r * 64 + kk2 * 32 + kg * 8, r)];
            #pragma unroll
            for (int df = 0; df < 8; ++df) {
                bf8v bw = gfrag(&WcTB[(size_t)(df * 16 + r) * N_ + n0 + kk2 * 32 + kg * 8]);
                cV[df] = __builtin_amdgcn_mfma_f32_16x16x32_bf16(pa, bw, cV[df], 0, 0, 0);
                cK[df] = __builtin_amdgcn_mfma_f32_16x16x32_bf16(pa2, bw, cK[df], 0, 0, 0);
            }
        }
    }

    // merge the two n-halves
    if (nh == 1) {
        #pragma unroll
        for (int df = 0; df < 8; ++df) {
            partK[mf][df][lane] = cK[df];
            partV[mf][df][lane] = cV[df];
        }
        partCs[mf][lane] = make_float4(csp[0], csp[1], csp[2], csp[3]);
    }
    __syncthreads();
    if (nh == 1) return;

    #pragma unroll
    for (int df = 0; df < 8; ++df) {
        cK[df] += partK[mf][df][lane];
        cV[df] += partV[mf][df][lane];
    }
    {
        float4 pc = partCs[mf][lane];
        csp[0] += pc.x; csp[1] += pc.y; csp[2] += pc.z; csp[3] += pc.w;
    }

    // cs reduce over 16 column-lanes (all lanes end with full sum)
    #pragma unroll
    for (int reg = 0; reg < 4; ++reg) {
        float v = csp[reg];
        v += __shfl_xor(v, 1, 16);
        v += __shfl_xor(v, 2, 16);
        v += __shfl_xor(v, 4, 16);
        v += __shfl_xor(v, 8, 16);
        csp[reg] = v;   // cs for row kg*4+reg
    }

    float rden[4], nrm[4], alpha4[4];
    #pragma unroll
    for (int reg = 0; reg < 4; ++reg) {
        float csv = csp[reg];
        alpha4[reg] = fminf(ge * csv * (1.0f / (float)N_), 1.0f);
        rden[reg] = 1.0f / fmaxf(csv, 1e-8f);
        float s = 0.0f;
        #pragma unroll
        for (int df = 0; df < 8; ++df) {
            float u = cK[df][reg] * rden[reg];
            s += u * u;
        }
        s += __shfl_xor(s, 1, 16);
        s += __shfl_xor(s, 2, 16);
        s += __shfl_xor(s, 4, 16);
        s += __shfl_xor(s, 8, 16);
        nrm[reg] = 1.0f / fmaxf(sqrtf(s), 1e-12f);
    }

    const float* KbG = emK + ((size_t)(bs * B_ + b)) * M_ + 0;   // row base below
    const float* KbR = emK + ((size_t)(bs * B_ + b)) * M_ * D_ + (size_t)mrow0 * D_;
    const float* VbR = emV + ((size_t)(bs * B_ + b)) * M_ * D_ + (size_t)mrow0 * D_;
    (void)KbG;
    float* oK = outK + (size_t)bs * M_ * D_ + (size_t)mrow0 * D_;
    float* oV = outV + (size_t)bs * M_ * D_ + (size_t)mrow0 * D_;
    #pragma unroll
    for (int reg = 0; reg < 4; ++reg) {
        int ml = kg * 4 + reg;
        float a = alpha4[reg];
        #pragma unroll
        for (int df = 0; df < 8; ++df) {
            int d = df * 16 + r;
            float uK = cK[df][reg] * rden[reg] * nrm[reg];
            float uV = cV[df][reg] * rden[reg];
            oK[ml * D_ + d] = (1.0f - a) * KbR[ml * D_ + d] + a * uK;
            oV[ml * D_ + d] = (1.0f - a) * VbR[ml * D_ + d] + a * uV;
        }
    }
    // outS / outA for this wave's 16 rows (lanes kg==0, row = r)
    if (kg == 0) {
        // fetch cs for row r from the lane group that owns it
        float cs0 = __shfl(csp[0], (r >> 2) * 16, 64);
        float cs1 = __shfl(csp[1], (r >> 2) * 16, 64);
        float cs2 = __shfl(csp[2], (r >> 2) * 16, 64);
        float cs3 = __shfl(csp[3], (r >> 2) * 16, 64);
        int sel = r & 3;
        float csv = (sel == 0) ? cs0 : (sel == 1) ? cs1 : (sel == 2) ? cs2 : cs3;
        float a = fminf(ge * csv * (1.0f / (float)N_), 1.0f);
        float sb = SbRow[r];
        float sp = fminf(fmaxf(sb + a, 0.0f), 3.0f);
        outS[(size_t)bs * M_ + mrow0 + r] = sp;
        outA[(size_t)bs * M_ + mrow0 + r] =
            emAge[((size_t)(bs * B_ + b)) * M_ + mrow0 + r] * (1.0f - a);
    }
}

// ---------------------------------------------------------------------------
__global__ __launch_bounds__(256) void scale_s_k(float* __restrict__ outS)
{
    __shared__ float wsum[4];
    const int bs = blockIdx.x, tid = threadIdx.x;
    float* p = outS + (size_t)bs * M_;
    float s = 0.0f;
    for (int i = tid; i < M_; i += 256) s += p[i];
    #pragma unroll
    for (int o = 32; o >= 1; o >>= 1) s += __shfl_xor(s, o, 64);
    if ((tid & 63) == 0) wsum[tid >> 6] = s;
    __syncthreads();
    float tot = wsum[0] + wsum[1] + wsum[2] + wsum[3];
    float scale = fminf(1.0f, 32.0f / fmaxf(tot, 1e-8f));
    for (int i = tid; i < M_; i += 256) p[i] *= scale;
}

// ---------------------------------------------------------------------------
extern "C" void kernel_launch(void* const* d_in, const int* in_sizes, int n_in,
                              void* d_out, int out_size, void* d_ws, size_t ws_size,
                              hipStream_t stream) {
    (void)in_sizes; (void)n_in; (void)out_size; (void)ws_size;
    const float* seed    = (const float*)d_in[0];
    const float* w_cand  = (const float*)d_in[1];
    const float* novelty = (const float*)d_in[2];
    const float* g_em    = (const float*)d_in[3];
    const float* emK     = (const float*)d_in[4];
    const float* emV     = (const float*)d_in[5];
    const float* emS     = (const float*)d_in[6];
    const float* emAge   = (const float*)d_in[7];
    const float* w1      = (const float*)d_in[8];
    const float* w2      = (const float*)d_in[9];
    const float* gb      = (const float*)d_in[10];
    const float* rt      = (const float*)d_in[11];
    const float* rtw     = (const float*)d_in[12];
    const int*   bp      = (const int*)d_in[13];

    float* out  = (float*)d_out;
    float* yem  = out;
    float* outK = out + 1048576;
    float* outV = out + 3145728;
    float* outS = out + 5242880;
    float* outA = out + 5259264;

    us_t* Kbf = (us_t*)d_ws;                               // [8][2048][128]
    us_t* Wcg = Kbf + (size_t)BS_ * M_ * D_;               // [8][1024][128]
    us_t* WcT = Wcg + (size_t)BS_ * N_ * D_;               // [8][128][1024]
    us_t* Vtg = WcT + (size_t)BS_ * D_ * N_;               // [8][128][2048]
    us_t* pDelta = Vtg + (size_t)BS_ * D_ * M_;            // [512][64][128]
    float* fb    = (float*)(pDelta + (size_t)512 * 64 * 128);
    float* invnW = fb;                                     // 8192
    float* mxW   = invnW + BS_ * N_;                       // 32768
    float* smW   = mxW + 4 * BS_ * N_;                     // 32768
    float4* cnsG = (float4*)(smW + 4 * BS_ * N_);          // 8192 float4
    float* y1    = (float*)(cnsG + BS_ * N_);              // 1,048,576
    float2* pML  = (float2*)(y1 + (size_t)BS_ * N_ * D_);  // 32768 float2

    conv_k<<<dim3(80, 8), 256, 0, stream>>>(w_cand, emK, emV, bp, Kbf, Wcg, WcT, Vtg, invnW);

    attn_part_k<<<dim3(512), 256, 0, stream>>>(seed, Kbf, Vtg, emS, rt, bp, pDelta, pML);
    attn_merge_k<<<dim3(128), 256, 0, stream>>>(seed, seed, pDelta, pML, w1, w2, gb, bp, y1, 0);
    attn_part_k<<<dim3(512), 256, 0, stream>>>(y1, Kbf, Vtg, emS, rt, bp, pDelta, pML);
    attn_merge_k<<<dim3(128), 256, 0, stream>>>(y1, seed, pDelta, pML, w1, w2, gb, bp, yem, 1);

    stats_k<<<dim3(512), 256, 0, stream>>>(Wcg, Kbf, invnW, emS, rtw, bp, mxW, smW);
    stats_fin_k<<<dim3(32), 256, 0, stream>>>(mxW, smW, novelty, invnW, cnsG);
    update3_k<<<dim3(512), 256, 0, stream>>>(Kbf, Wcg, WcT, g_em, emK, emV, emS, emAge,
                                             rtw, bp, cnsG, outK, outV, outS, outA);
    scale_s_k<<<8, 256, 0, stream>>>(outS);
}

// Round 7
// 294.134 us; speedup vs baseline: 1.3652x; 1.3652x over previous
//
#include <hip/hip_runtime.h>
#include <hip/hip_bf16.h>
#include <math.h>

#define BS_ 8
#define B_  4
#define M_  2048
#define D_  128
#define N_  1024
#define NEG (-1e30f)

typedef unsigned short us_t;
typedef __attribute__((ext_vector_type(8))) short bf8v;   // 8 bf16 (A/B frag)
typedef __attribute__((ext_vector_type(4))) float f4v;    // C/D frag

__device__ __forceinline__ float softplus_(float x) {
    return (x > 20.0f) ? x : log1pf(expf(x));
}
__device__ __forceinline__ float dot4_acc(float4 a, float4 b, float acc) {
    acc = fmaf(a.x, b.x, acc);
    acc = fmaf(a.y, b.y, acc);
    acc = fmaf(a.z, b.z, acc);
    acc = fmaf(a.w, b.w, acc);
    return acc;
}
__device__ __forceinline__ us_t f2bf(float x) {
    __hip_bfloat16 h = __float2bfloat16(x);   // RNE
    return __builtin_bit_cast(us_t, h);
}
__device__ __forceinline__ float bf2f(us_t u) {
    unsigned v = ((unsigned)u) << 16;
    return __builtin_bit_cast(float, v);
}
__device__ __forceinline__ bf8v gfrag(const us_t* p) { return *(const bf8v*)p; }  // 16B L2 load
// LDS swizzle: XOR bits 3-5 of ushort index with row&7
__device__ __forceinline__ int swz(int us_idx, int row) { return us_idx ^ ((row & 7) << 3); }

// ---------------------------------------------------------------------------
// conv_k: f32 -> bf16 conversions into ws (round-4 proven).
// ---------------------------------------------------------------------------
__global__ __launch_bounds__(256, 2) void conv_k(
    const float* __restrict__ w_cand, const float* __restrict__ emK,
    const float* __restrict__ emV, const int* __restrict__ bp,
    us_t* __restrict__ Kbf, us_t* __restrict__ Wcg,
    us_t* __restrict__ WcTg, us_t* __restrict__ Vtg, float* __restrict__ invnW)
{
    __shared__ float wt[64][132];
    __shared__ float invn[64];
    const int tid = threadIdx.x;
    const int bs  = blockIdx.y;
    const int bx  = blockIdx.x;
    const int b   = bp[0];

    if (bx < 32) {
        const float* src = emK + ((size_t)(bs * B_ + b)) * M_ * D_ + (size_t)bx * 64 * D_;
        us_t* dst = Kbf + (size_t)bs * M_ * D_ + (size_t)bx * 64 * D_;
        for (int i = tid; i < 64 * 128 / 4; i += 256) {
            float4 v = ((const float4*)src)[i];
            ushort4 o;
            o.x = f2bf(v.x); o.y = f2bf(v.y); o.z = f2bf(v.z); o.w = f2bf(v.w);
            ((ushort4*)dst)[i] = o;
        }
        return;
    }
    if (bx >= 48) {
        const int m0 = (bx - 48) * 64;
        const float* Vb = emV + ((size_t)(bs * B_ + b)) * M_ * D_ + (size_t)m0 * D_;
        for (int c = tid; c < 64 * 32; c += 256) {
            int row = c >> 5, col = (c & 31) << 2;
            *(float4*)&wt[row][col] = *(const float4*)&Vb[row * D_ + col];
        }
        __syncthreads();
        us_t* VtB = Vtg + (size_t)bs * D_ * M_;
        for (int c = tid; c < 1024; c += 256) {
            int d = c >> 3, mc = c & 7;
            uint4 o;
            o.x = (unsigned)f2bf(wt[mc * 8 + 0][d]) | ((unsigned)f2bf(wt[mc * 8 + 1][d]) << 16);
            o.y = (unsigned)f2bf(wt[mc * 8 + 2][d]) | ((unsigned)f2bf(wt[mc * 8 + 3][d]) << 16);
            o.z = (unsigned)f2bf(wt[mc * 8 + 4][d]) | ((unsigned)f2bf(wt[mc * 8 + 5][d]) << 16);
            o.w = (unsigned)f2bf(wt[mc * 8 + 6][d]) | ((unsigned)f2bf(wt[mc * 8 + 7][d]) << 16);
            *(uint4*)&VtB[(size_t)d * M_ + m0 + mc * 8] = o;
        }
        return;
    }
    const int n0 = (bx - 32) * 64;
    const float* Wb = w_cand + (size_t)bs * N_ * D_ + (size_t)n0 * D_;
    for (int c = tid; c < 64 * 32; c += 256) {
        int row = c >> 5, col = (c & 31) << 2;
        *(float4*)&wt[row][col] = *(const float4*)&Wb[row * D_ + col];
    }
    __syncthreads();
    {
        int r = tid >> 2, j = tid & 3;
        float ss = 0.0f;
        #pragma unroll
        for (int q = 0; q < 8; ++q) {
            float4 v = *(float4*)&wt[r][q * 16 + j * 4];
            ss = dot4_acc(v, v, ss);
        }
        ss += __shfl_xor(ss, 1, 4);
        ss += __shfl_xor(ss, 2, 4);
        if (j == 0) invn[r] = 1.0f / fmaxf(sqrtf(ss), 1e-12f);
    }
    __syncthreads();
    us_t* WcB = Wcg + (size_t)bs * N_ * D_ + (size_t)n0 * D_;
    for (int e = tid; e < 8192; e += 256) {
        int row = e >> 7, col = e & 127;
        WcB[row * D_ + col] = f2bf(wt[row][col]);
    }
    us_t* WcTB = WcTg + (size_t)bs * D_ * N_;
    for (int e = tid; e < 8192; e += 256) {
        int d = e >> 6, n = e & 63;
        WcTB[d * N_ + n0 + n] = f2bf(wt[n][d]);
    }
    if (tid < 64) invnW[(size_t)bs * N_ + n0 + tid] = invn[tid];
}

// ---------------------------------------------------------------------------
// attn_part_k: flash-attention partial over one M-quarter (round-4 proven:
// double-buffered LDS staging). 512 blocks, 4 waves x 16 n-rows.
// ---------------------------------------------------------------------------
__global__ __launch_bounds__(256, 2) void attn_part_k(
    const float* __restrict__ ySrc, const us_t* __restrict__ Kbf,
    const us_t* __restrict__ Vtg, const float* __restrict__ emS,
    const float* __restrict__ raw_tau, const int* __restrict__ bp,
    us_t* __restrict__ pDelta, float2* __restrict__ pML)
{
    __shared__ us_t KtL[2][8192];
    __shared__ us_t VtL[2][8192];
    __shared__ us_t Pl[4][1024];
    __shared__ float sbt[2][64];

    const int tid = threadIdx.x;
    const int raw = blockIdx.x;
    const int logical = (raw & 7) * 64 + (raw >> 3);   // 512 = 8 XCD * 64
    const int bs = logical >> 6;
    const int rem = logical & 63;
    const int nt = rem >> 2;
    const int q  = rem & 3;
    const int b = bp[0];
    const float rtau = 1.0f / (softplus_(raw_tau[b]) + 0.1f);

    const us_t* KbB = Kbf + (size_t)bs * M_ * D_ + (size_t)(q * 512) * D_;
    const us_t* VtB = Vtg + (size_t)bs * D_ * M_;
    const float* SbB = emS + ((size_t)(bs * B_ + b)) * M_ + q * 512;

    const int wave = tid >> 6, lane = tid & 63;
    const int r = lane & 15, kg = lane >> 4;

    bf8v yb[4];
    {
        const float* yrow = ySrc + ((size_t)bs * N_ + nt * 64 + wave * 16 + r) * D_;
        #pragma unroll
        for (int kk = 0; kk < 4; ++kk) {
            float4 a = *(const float4*)&yrow[kk * 32 + kg * 8];
            float4 c = *(const float4*)&yrow[kk * 32 + kg * 8 + 4];
            bf8v t;
            t[0] = (short)f2bf(a.x); t[1] = (short)f2bf(a.y);
            t[2] = (short)f2bf(a.z); t[3] = (short)f2bf(a.w);
            t[4] = (short)f2bf(c.x); t[5] = (short)f2bf(c.y);
            t[6] = (short)f2bf(c.z); t[7] = (short)f2bf(c.w);
            yb[kk] = t;
        }
    }

    uint4 kr[4], vr[4];
    float sreg = 0.0f;

#define AP_LOAD(t) do {                                                           \
        for (int i = 0; i < 4; ++i) {                                             \
            int c = tid + i * 256;                                                \
            kr[i] = *(const uint4*)&KbB[(size_t)((t) * 64 + (c >> 4)) * D_ + ((c & 15) << 3)]; \
            vr[i] = *(const uint4*)&VtB[(size_t)(c >> 3) * M_ + q * 512 + (t) * 64 + ((c & 7) << 3)]; \
        }                                                                         \
        if (tid < 64) sreg = SbB[(t) * 64 + tid];                                 \
    } while (0)

#define AP_WRITE(bf) do {                                                         \
        for (int i = 0; i < 4; ++i) {                                             \
            int c = tid + i * 256;                                                \
            int ki = (c >> 4) * 128 + ((c & 15) << 3);                            \
            *(uint4*)&KtL[bf][swz(ki, c >> 4)] = kr[i];                           \
            int vi = (c >> 3) * 64 + ((c & 7) << 3);                              \
            *(uint4*)&VtL[bf][swz(vi, c >> 3)] = vr[i];                           \
        }                                                                         \
        if (tid < 64) sbt[bf][tid] = sreg;                                        \
    } while (0)

    f4v cD[8];
    #pragma unroll
    for (int df = 0; df < 8; ++df) cD[df] = (f4v){0.f, 0.f, 0.f, 0.f};
    float mrun = NEG, lsum = 0.0f;

    AP_LOAD(0);
    AP_WRITE(0);
    __syncthreads();

    for (int t = 0; t < 8; ++t) {
        const int cur = t & 1;
        if (t < 7) AP_LOAD(t + 1);

        float sv[4][4];
        #pragma unroll
        for (int mf = 0; mf < 4; ++mf) {
            f4v c4 = {0.f, 0.f, 0.f, 0.f};
            #pragma unroll
            for (int kk = 0; kk < 4; ++kk) {
                int row_ = mf * 16 + r;
                bf8v a = *(bf8v*)&KtL[cur][swz(row_ * 128 + kk * 32 + kg * 8, row_)];
                c4 = __builtin_amdgcn_mfma_f32_16x16x32_bf16(a, yb[kk], c4, 0, 0, 0);
            }
            #pragma unroll
            for (int reg = 0; reg < 4; ++reg) {
                int ml = mf * 16 + kg * 4 + reg;
                sv[mf][reg] = (sbt[cur][ml] > 0.0f) ? c4[reg] * rtau : NEG;
            }
        }
        float tmax = NEG;
        #pragma unroll
        for (int mf = 0; mf < 4; ++mf)
            #pragma unroll
            for (int reg = 0; reg < 4; ++reg) tmax = fmaxf(tmax, sv[mf][reg]);
        tmax = fmaxf(tmax, __shfl_xor(tmax, 16, 64));
        tmax = fmaxf(tmax, __shfl_xor(tmax, 32, 64));
        float mnew = fmaxf(mrun, tmax);
        float f = (mnew > -1e29f) ? __expf(mrun - mnew) : 1.0f;
        mrun = mnew;

        float psum = 0.0f;
        #pragma unroll
        for (int mf = 0; mf < 4; ++mf)
            #pragma unroll
            for (int reg = 0; reg < 4; ++reg) {
                float p = (sv[mf][reg] > -1e29f) ? __expf(sv[mf][reg] - mnew) : 0.0f;
                psum += p;
                int ml = mf * 16 + kg * 4 + reg;
                Pl[wave][swz(r * 64 + ml, r)] = f2bf(p);
            }
        lsum = lsum * f + psum;

        float fr[4];
        #pragma unroll
        for (int reg = 0; reg < 4; ++reg) fr[reg] = __shfl(f, kg * 4 + reg, 64);
        #pragma unroll
        for (int df = 0; df < 8; ++df)
            #pragma unroll
            for (int reg = 0; reg < 4; ++reg) cD[df][reg] *= fr[reg];

        #pragma unroll
        for (int kk = 0; kk < 2; ++kk) {
            bf8v pa = *(bf8v*)&Pl[wave][swz(r * 64 + kk * 32 + kg * 8, r)];
            #pragma unroll
            for (int df = 0; df < 8; ++df) {
                int row_ = df * 16 + r;
                bf8v bv = *(bf8v*)&VtL[cur][swz(row_ * 64 + kk * 32 + kg * 8, row_)];
                cD[df] = __builtin_amdgcn_mfma_f32_16x16x32_bf16(pa, bv, cD[df], 0, 0, 0);
            }
        }

        if (t < 7) AP_WRITE(cur ^ 1);
        __syncthreads();
    }
#undef AP_LOAD
#undef AP_WRITE

    lsum += __shfl_xor(lsum, 16, 64);
    lsum += __shfl_xor(lsum, 32, 64);
    float invl = (lsum > 0.0f) ? 1.0f / lsum : 0.0f;

    us_t* pd = pDelta + ((size_t)((bs * 16 + nt) * 4 + q)) * (64 * 128);
    #pragma unroll
    for (int reg = 0; reg < 4; ++reg) {
        float il = __shfl(invl, kg * 4 + reg, 64);
        int nrow = wave * 16 + kg * 4 + reg;
        #pragma unroll
        for (int df = 0; df < 8; ++df)
            pd[nrow * 128 + df * 16 + r] = f2bf(cD[df][reg] * il);
    }
    if (kg == 0) {
        int nrow = wave * 16 + r;
        pML[((size_t)((bs * 16 + nt) * 4 + q)) * 64 + nrow] = make_float2(mrun, lsum);
    }
}

// ---------------------------------------------------------------------------
// attn_merge_k: merge 4 quarters, gate, update y (round-4 proven).
// ---------------------------------------------------------------------------
__global__ __launch_bounds__(256, 2) void attn_merge_k(
    const float* __restrict__ ySrc, const float* __restrict__ seed,
    const us_t* __restrict__ pDelta, const float2* __restrict__ pML,
    const float* __restrict__ w1, const float* __restrict__ w2,
    const float* __restrict__ gb, const int* __restrict__ bp,
    float* __restrict__ yOut, int mode)
{
    __shared__ float w1L[128], w2L[128], gbL[128];
    const int tid = threadIdx.x, raw = blockIdx.x;
    const int logical = (raw & 7) * 16 + (raw >> 3);
    const int bs = logical >> 4, nt = logical & 15;
    const int b = bp[0];
    if (tid < 128) {
        w1L[tid] = w1[b * D_ + tid];
        w2L[tid] = w2[b * D_ + tid];
        gbL[tid] = gb[b * D_ + tid];
    }
    __syncthreads();
    const int rw = tid >> 2, dj = tid & 3;
    const size_t base = ((size_t)(bs * 16 + nt)) * 4;
    float2 ml0 = pML[(base + 0) * 64 + rw];
    float2 ml1 = pML[(base + 1) * 64 + rw];
    float2 ml2 = pML[(base + 2) * 64 + rw];
    float2 ml3 = pML[(base + 3) * 64 + rw];
    float M = fmaxf(fmaxf(ml0.x, ml1.x), fmaxf(ml2.x, ml3.x));
    float w0 = 0.f, wA = 0.f, wB = 0.f, w3 = 0.f, tot = 0.f;
    if (M > -1e29f) {
        w0 = ml0.y * __expf(ml0.x - M);
        wA = ml1.y * __expf(ml1.x - M);
        wB = ml2.y * __expf(ml2.x - M);
        w3 = ml3.y * __expf(ml3.x - M);
        tot = w0 + wA + wB + w3;
    }
    float inv = (tot > 0.0f) ? 1.0f / tot : 0.0f;
    w0 *= inv; wA *= inv; wB *= inv; w3 *= inv;

    const us_t* pd0 = pDelta + (base + 0) * 8192 + rw * 128;
    const us_t* pd1 = pDelta + (base + 1) * 8192 + rw * 128;
    const us_t* pd2 = pDelta + (base + 2) * 8192 + rw * 128;
    const us_t* pd3 = pDelta + (base + 3) * 8192 + rw * 128;
    const float* yrow = ySrc + ((size_t)bs * N_ + nt * 64 + rw) * D_;
    const float* srow = seed + ((size_t)bs * N_ + nt * 64 + rw) * D_;
    float* orow = yOut + ((size_t)bs * N_ + nt * 64 + rw) * D_;

    #pragma unroll
    for (int e = 0; e < 4; ++e) {
        int d0 = dj * 32 + e * 8;
        uint4 u0 = *(const uint4*)&pd0[d0];
        uint4 u1 = *(const uint4*)&pd1[d0];
        uint4 u2 = *(const uint4*)&pd2[d0];
        uint4 u3 = *(const uint4*)&pd3[d0];
        const us_t* a0 = (const us_t*)&u0;
        const us_t* a1 = (const us_t*)&u1;
        const us_t* a2 = (const us_t*)&u2;
        const us_t* a3 = (const us_t*)&u3;
        float4 ya = *(const float4*)&yrow[d0];
        float4 yc = *(const float4*)&yrow[d0 + 4];
        float yv[8] = {ya.x, ya.y, ya.z, ya.w, yc.x, yc.y, yc.z, yc.w};
        float res[8];
        #pragma unroll
        for (int j = 0; j < 8; ++j) {
            float dl = w0 * bf2f(a0[j]) + wA * bf2f(a1[j]) + wB * bf2f(a2[j]) + w3 * bf2f(a3[j]);
            int d = d0 + j;
            float g = 1.0f / (1.0f + __expf(-(w1L[d] * yv[j] + w2L[d] * dl + gbL[d])));
            res[j] = yv[j] + g * dl;
        }
        if (mode == 1) {
            float4 sa = *(const float4*)&srow[d0];
            float4 sc = *(const float4*)&srow[d0 + 4];
            res[0] -= sa.x; res[1] -= sa.y; res[2] -= sa.z; res[3] -= sa.w;
            res[4] -= sc.x; res[5] -= sc.y; res[6] -= sc.z; res[7] -= sc.w;
        }
        float4 o1; o1.x = res[0]; o1.y = res[1]; o1.z = res[2]; o1.w = res[3];
        float4 o2; o2.x = res[4]; o2.y = res[5]; o2.z = res[6]; o2.w = res[7];
        *(float4*)&orow[d0] = o1;
        *(float4*)&orow[d0 + 4] = o2;
    }
}

// ---------------------------------------------------------------------------
// stats_k: routing score stats over one M-quarter (round-4 proven, dbuf).
// ---------------------------------------------------------------------------
__global__ __launch_bounds__(256, 2) void stats_k(
    const us_t* __restrict__ Wcg, const us_t* __restrict__ Kbf,
    const float* __restrict__ invnW, const float* __restrict__ emS,
    const float* __restrict__ raw_tau_w, const int* __restrict__ bp,
    float* __restrict__ mxW, float* __restrict__ smW)
{
    __shared__ us_t KtL[2][8192];
    __shared__ float sbt[2][64];

    const int tid = threadIdx.x;
    const int raw = blockIdx.x;
    const int logical = (raw & 7) * 64 + (raw >> 3);
    const int bs = logical >> 6;
    const int rem = logical & 63;
    const int nt = rem >> 2;
    const int q  = rem & 3;
    const int b = bp[0];
    const float rtw = 1.0f / (softplus_(raw_tau_w[b]) + 0.1f);

    const us_t* KbB = Kbf + (size_t)bs * M_ * D_ + (size_t)(q * 512) * D_;
    const float* SbB = emS + ((size_t)(bs * B_ + b)) * M_ + q * 512;

    const int wave = tid >> 6, lane = tid & 63;
    const int r = lane & 15, kg = lane >> 4;
    const int n = nt * 64 + wave * 16 + r;

    bf8v wb[4];
    {
        const us_t* wrow = Wcg + ((size_t)bs * N_ + n) * D_;
        #pragma unroll
        for (int kk = 0; kk < 4; ++kk)
            wb[kk] = gfrag(&wrow[kk * 32 + kg * 8]);
    }
    const float ivn = invnW[(size_t)bs * N_ + n];

    uint4 kr[4];
    float sreg = 0.0f;

#define ST_LOAD(t) do {                                                           \
        for (int i = 0; i < 4; ++i) {                                             \
            int c = tid + i * 256;                                                \
            kr[i] = *(const uint4*)&KbB[(size_t)((t) * 64 + (c >> 4)) * D_ + ((c & 15) << 3)]; \
        }                                                                         \
        if (tid < 64) sreg = SbB[(t) * 64 + tid];                                 \
    } while (0)

#define ST_WRITE(bf) do {                                                         \
        for (int i = 0; i < 4; ++i) {                                             \
            int c = tid + i * 256;                                                \
            int ki = (c >> 4) * 128 + ((c & 15) << 3);                            \
            *(uint4*)&KtL[bf][swz(ki, c >> 4)] = kr[i];                           \
        }                                                                         \
        if (tid < 64) sbt[bf][tid] = sreg;                                        \
    } while (0)

    float mx = NEG, sm = 0.0f;

    ST_LOAD(0);
    ST_WRITE(0);
    __syncthreads();

    for (int t = 0; t < 8; ++t) {
        const int cur = t & 1;
        if (t < 7) ST_LOAD(t + 1);

        #pragma unroll
        for (int mf = 0; mf < 4; ++mf) {
            f4v c4 = {0.f, 0.f, 0.f, 0.f};
            #pragma unroll
            for (int kk = 0; kk < 4; ++kk) {
                int row_ = mf * 16 + r;
                bf8v a = *(bf8v*)&KtL[cur][swz(row_ * 128 + kk * 32 + kg * 8, row_)];
                c4 = __builtin_amdgcn_mfma_f32_16x16x32_bf16(a, wb[kk], c4, 0, 0, 0);
            }
            float v[4]; bool act[4];
            float lm = NEG;
            #pragma unroll
            for (int reg = 0; reg < 4; ++reg) {
                int ml = mf * 16 + kg * 4 + reg;
                v[reg] = c4[reg] * ivn * rtw;
                act[reg] = (sbt[cur][ml] > 0.0f);
                if (act[reg]) lm = fmaxf(lm, v[reg]);
            }
            float mnew = fmaxf(mx, lm);
            if (mnew > -1e29f) {
                float acc = sm * __expf(mx - mnew);
                #pragma unroll
                for (int reg = 0; reg < 4; ++reg)
                    if (act[reg]) acc += __expf(v[reg] - mnew);
                sm = acc; mx = mnew;
            }
        }

        if (t < 7) ST_WRITE(cur ^ 1);
        __syncthreads();
    }
#undef ST_LOAD
#undef ST_WRITE

    #pragma unroll
    for (int off = 16; off <= 32; off <<= 1) {
        float omx = __shfl_xor(mx, off, 64);
        float osm = __shfl_xor(sm, off, 64);
        float nm = fmaxf(mx, omx);
        if (nm > -1e29f) sm = sm * __expf(mx - nm) + osm * __expf(omx - nm);
        else sm = 0.0f;
        mx = nm;
    }
    if (kg == 0) {
        mxW[(size_t)(q * BS_ + bs) * N_ + n] = mx;
        smW[(size_t)(q * BS_ + bs) * N_ + n] = sm;
    }
}

// ---------------------------------------------------------------------------
// stats_fin_k: merge 4 quarters -> per-n softmax constants (round-4 proven).
// ---------------------------------------------------------------------------
__global__ __launch_bounds__(256) void stats_fin_k(
    const float* __restrict__ mxW, const float* __restrict__ smW,
    const float* __restrict__ novelty,
    float* __restrict__ mxF, float* __restrict__ rivF, float* __restrict__ punF)
{
    int idx = blockIdx.x * 256 + threadIdx.x;   // 32 blocks * 256 = 8192
    float m[4], s[4];
    #pragma unroll
    for (int q = 0; q < 4; ++q) {
        m[q] = mxW[q * (BS_ * N_) + idx];
        s[q] = smW[q * (BS_ * N_) + idx];
    }
    float MX = fmaxf(fmaxf(m[0], m[1]), fmaxf(m[2], m[3]));
    float SM = 0.0f;
    if (MX > -1e29f) {
        #pragma unroll
        for (int q = 0; q < 4; ++q)
            if (m[q] > -1e29f) SM += s[q] * __expf(m[q] - MX);
    }
    float nov = novelty[idx];
    if (SM > 0.0f) { mxF[idx] = MX; rivF[idx] = nov / SM; punF[idx] = -1.0f; }
    else           { mxF[idx] = 0.0f; rivF[idx] = 0.0f; punF[idx] = nov * (1.0f / (float)M_); }
}

// ---------------------------------------------------------------------------
// update4_k: 512 blocks = (bs x 64 m-tiles of 32 rows). 4 waves =
// 2 m-frags x 2 column-halves of each staged n-tile (shared staging).
// Single-buffered Wc/WcT staging w/ reg prefetch 2 tiles ahead; LDS 43KB
// -> 2 blocks/CU. Column-half merge via LDS union over staging buffer.
// ---------------------------------------------------------------------------
__global__ __launch_bounds__(256) void update4_k(
    const us_t* __restrict__ Kbf, const us_t* __restrict__ Wcg,
    const us_t* __restrict__ WcTg, const float* __restrict__ g_em,
    const float* __restrict__ emK, const float* __restrict__ emV,
    const float* __restrict__ emS, const float* __restrict__ emAge,
    const float* __restrict__ raw_tau_w, const int* __restrict__ bp,
    const float* __restrict__ invnW, const float* __restrict__ mxF,
    const float* __restrict__ rivF, const float* __restrict__ punF,
    float* __restrict__ outK, float* __restrict__ outV,
    float* __restrict__ outS, float* __restrict__ outA)
{
    __shared__ __align__(16) char smraw[32768];   // staging, reused for merge
    us_t* WcS  = (us_t*)smraw;             // [64n][128d]
    us_t* WcTS = (us_t*)(smraw + 16384);   // [128d][64n]
    __shared__ us_t Pl[2][1024];           // per-mf P tiles [16m][64n]
    __shared__ us_t P2l[2][1024];
    __shared__ float4 cns[64];
    __shared__ float4 pcs[2][64];

    const int tid = threadIdx.x;
    const int raw = blockIdx.x;
    const int logical = (raw & 7) * 64 + (raw >> 3);   // 512 = 8 XCD * 64
    const int bs = logical >> 6;
    const int m0 = (logical & 63) * 32;
    const int b = bp[0];
    const float rtw = 1.0f / (softplus_(raw_tau_w[b]) + 0.1f);
    const float ge = g_em[bs];

    const int wave = tid >> 6, lane = tid & 63;
    const int mf = wave & 1, nfh = wave >> 1;
    const int r = lane & 15, kg = lane >> 4;
    const int mrow0 = m0 + mf * 16;

    const us_t* WcB  = Wcg + (size_t)bs * N_ * D_;
    const us_t* WcTB = WcTg + (size_t)bs * D_ * N_;
    const float* SbRow = emS + ((size_t)(bs * B_ + b)) * M_ + mrow0;

    // A fragments (K rows), loaded once (L2-direct is fine for one-shot loads)
    bf8v a_s[4];
    {
        const us_t* arow = Kbf + ((size_t)bs * M_ + mrow0 + r) * D_;
        #pragma unroll
        for (int kk = 0; kk < 4; ++kk)
            a_s[kk] = gfrag(&arow[kk * 32 + kg * 8]);
    }
    bool act4[4];
    #pragma unroll
    for (int reg = 0; reg < 4; ++reg) act4[reg] = (SbRow[kg * 4 + reg] > 0.0f);

    f4v cK[8], cV[8];
    #pragma unroll
    for (int df = 0; df < 8; ++df) { cK[df] = (f4v){0,0,0,0}; cV[df] = (f4v){0,0,0,0}; }
    float csp[4] = {0.f, 0.f, 0.f, 0.f};

    uint4 wr[4], wtr[4];
    float4 creg = {0.f, 0.f, 0.f, 0.f};

#define U4_LOAD(t) do {                                                            \
        for (int i = 0; i < 4; ++i) {                                              \
            int c = tid + i * 256;                                                 \
            wr[i]  = *(const uint4*)&WcB[((size_t)((t) * 64 + (c >> 4))) * D_ + ((c & 15) << 3)]; \
            wtr[i] = *(const uint4*)&WcTB[((size_t)(c >> 3)) * N_ + (t) * 64 + ((c & 7) << 3)];   \
        }                                                                          \
        if (tid < 64) {                                                            \
            int nn = (t) * 64 + tid;                                               \
            creg.x = mxF[(size_t)bs * N_ + nn];                                    \
            creg.y = rivF[(size_t)bs * N_ + nn];                                   \
            creg.z = punF[(size_t)bs * N_ + nn];                                   \
            creg.w = invnW[(size_t)bs * N_ + nn];                                  \
        }                                                                          \
    } while (0)

#define U4_WRITE() do {                                                            \
        for (int i = 0; i < 4; ++i) {                                              \
            int c = tid + i * 256;                                                 \
            int ki = (c >> 4) * 128 + ((c & 15) << 3);                             \
            *(uint4*)&WcS[swz(ki, c >> 4)] = wr[i];                                \
            int vi = (c >> 3) * 64 + ((c & 7) << 3);                               \
            *(uint4*)&WcTS[swz(vi, c >> 3)] = wtr[i];                              \
        }                                                                          \
        if (tid < 64) cns[tid] = creg;                                             \
    } while (0)

    U4_LOAD(0);
    U4_WRITE();
    U4_LOAD(1);
    __syncthreads();

    for (int nt = 0; nt < 16; ++nt) {
        // scores + P/P2 for this wave's two 16-col groups (cols nfh*32..+31)
        #pragma unroll
        for (int nf2 = 0; nf2 < 2; ++nf2) {
            const int nf = nfh * 2 + nf2;
            f4v c = {0.f, 0.f, 0.f, 0.f};
            #pragma unroll
            for (int kk = 0; kk < 4; ++kk) {
                int row = nf * 16 + r;
                bf8v bb = *(bf8v*)&WcS[swz(row * 128 + kk * 32 + kg * 8, row)];
                c = __builtin_amdgcn_mfma_f32_16x16x32_bf16(a_s[kk], bb, c, 0, 0, 0);
            }
            int nl = nf * 16 + r;
            float4 cn = cns[nl];
            #pragma unroll
            for (int reg = 0; reg < 4; ++reg) {
                float p;
                if (cn.z >= 0.0f) p = cn.z;
                else p = act4[reg] ? cn.y * __expf(c[reg] * cn.w * rtw - cn.x) : 0.0f;
                csp[reg] += p;
                int mr = kg * 4 + reg;
                Pl[mf][swz(mr * 64 + nl, mr)] = f2bf(p);
                P2l[mf][swz(mr * 64 + nl, mr)] = f2bf(p * cn.w);
            }
        }
        // update GEMMs: this wave covers k-slot nfh (cols it just wrote)
        {
            bf8v pa  = *(bf8v*)&Pl[mf][swz(r * 64 + nfh * 32 + kg * 8, r)];
            bf8v pa2 = *(bf8v*)&P2l[mf][swz(r * 64 + nfh * 32 + kg * 8, r)];
            #pragma unroll
            for (int df = 0; df < 8; ++df) {
                int row = df * 16 + r;
                bf8v bw = *(bf8v*)&WcTS[swz(row * 64 + nfh * 32 + kg * 8, row)];
                cV[df] = __builtin_amdgcn_mfma_f32_16x16x32_bf16(pa, bw, cV[df], 0, 0, 0);
                cK[df] = __builtin_amdgcn_mfma_f32_16x16x32_bf16(pa2, bw, cK[df], 0, 0, 0);
            }
        }
        if (nt < 15) {
            __syncthreads();            // everyone done reading stage
            U4_WRITE();                 // waits on prefetch regs (vmcnt)
            if (nt + 2 < 16) U4_LOAD(nt + 2);
            __syncthreads();            // stage ready
        }
    }
#undef U4_LOAD
#undef U4_WRITE

    // merge the two column-halves (reuse staging LDS)
    __syncthreads();
    f4v* pK = (f4v*)smraw;              // [2][8][64]
    f4v* pV = (f4v*)(smraw + 16384);
    if (nfh == 1) {
        #pragma unroll
        for (int df = 0; df < 8; ++df) {
            pK[(mf * 8 + df) * 64 + lane] = cK[df];
            pV[(mf * 8 + df) * 64 + lane] = cV[df];
        }
        pcs[mf][lane] = make_float4(csp[0], csp[1], csp[2], csp[3]);
    }
    __syncthreads();
    if (nfh == 1) return;

    #pragma unroll
    for (int df = 0; df < 8; ++df) {
        cK[df] += pK[(mf * 8 + df) * 64 + lane];
        cV[df] += pV[(mf * 8 + df) * 64 + lane];
    }
    {
        float4 pc = pcs[mf][lane];
        csp[0] += pc.x; csp[1] += pc.y; csp[2] += pc.z; csp[3] += pc.w;
    }

    // cs reduce over the 16 column-lanes
    #pragma unroll
    for (int reg = 0; reg < 4; ++reg) {
        float v = csp[reg];
        v += __shfl_xor(v, 1, 16);
        v += __shfl_xor(v, 2, 16);
        v += __shfl_xor(v, 4, 16);
        v += __shfl_xor(v, 8, 16);
        csp[reg] = v;   // cs for row kg*4+reg
    }

    float rden[4], nrm[4], alpha4[4];
    #pragma unroll
    for (int reg = 0; reg < 4; ++reg) {
        float csv = csp[reg];
        alpha4[reg] = fminf(ge * csv * (1.0f / (float)N_), 1.0f);
        rden[reg] = 1.0f / fmaxf(csv, 1e-8f);
        float s = 0.0f;
        #pragma unroll
        for (int df = 0; df < 8; ++df) {
            float u = cK[df][reg] * rden[reg];
            s += u * u;
        }
        s += __shfl_xor(s, 1, 16);
        s += __shfl_xor(s, 2, 16);
        s += __shfl_xor(s, 4, 16);
        s += __shfl_xor(s, 8, 16);
        nrm[reg] = 1.0f / fmaxf(sqrtf(s), 1e-12f);
    }

    const float* KbR = emK + ((size_t)(bs * B_ + b)) * M_ * D_ + (size_t)mrow0 * D_;
    const float* VbR = emV + ((size_t)(bs * B_ + b)) * M_ * D_ + (size_t)mrow0 * D_;
    float* oK = outK + (size_t)bs * M_ * D_ + (size_t)mrow0 * D_;
    float* oV = outV + (size_t)bs * M_ * D_ + (size_t)mrow0 * D_;
    #pragma unroll
    for (int reg = 0; reg < 4; ++reg) {
        int ml = kg * 4 + reg;
        float a = alpha4[reg];
        #pragma unroll
        for (int df = 0; df < 8; ++df) {
            int d = df * 16 + r;
            float uK = cK[df][reg] * rden[reg] * nrm[reg];
            float uV = cV[df][reg] * rden[reg];
            oK[ml * D_ + d] = (1.0f - a) * KbR[ml * D_ + d] + a * uK;
            oV[ml * D_ + d] = (1.0f - a) * VbR[ml * D_ + d] + a * uV;
        }
    }
    // outS / outA for this wave's 16 rows (shfl hoisted out of the branch)
    float cs0 = __shfl(csp[0], (r >> 2) * 16, 64);
    float cs1 = __shfl(csp[1], (r >> 2) * 16, 64);
    float cs2 = __shfl(csp[2], (r >> 2) * 16, 64);
    float cs3 = __shfl(csp[3], (r >> 2) * 16, 64);
    if (kg == 0) {
        int sel = r & 3;
        float csv = (sel == 0) ? cs0 : (sel == 1) ? cs1 : (sel == 2) ? cs2 : cs3;
        float a = fminf(ge * csv * (1.0f / (float)N_), 1.0f);
        float sb = SbRow[r];
        float sp = fminf(fmaxf(sb + a, 0.0f), 3.0f);
        outS[(size_t)bs * M_ + mrow0 + r] = sp;
        outA[(size_t)bs * M_ + mrow0 + r] =
            emAge[((size_t)(bs * B_ + b)) * M_ + mrow0 + r] * (1.0f - a);
    }
}

// ---------------------------------------------------------------------------
__global__ __launch_bounds__(256) void scale_s_k(float* __restrict__ outS)
{
    __shared__ float wsum[4];
    const int bs = blockIdx.x, tid = threadIdx.x;
    float* p = outS + (size_t)bs * M_;
    float s = 0.0f;
    for (int i = tid; i < M_; i += 256) s += p[i];
    #pragma unroll
    for (int o = 32; o >= 1; o >>= 1) s += __shfl_xor(s, o, 64);
    if ((tid & 63) == 0) wsum[tid >> 6] = s;
    __syncthreads();
    float tot = wsum[0] + wsum[1] + wsum[2] + wsum[3];
    float scale = fminf(1.0f, 32.0f / fmaxf(tot, 1e-8f));
    for (int i = tid; i < M_; i += 256) p[i] *= scale;
}

// ---------------------------------------------------------------------------
extern "C" void kernel_launch(void* const* d_in, const int* in_sizes, int n_in,
                              void* d_out, int out_size, void* d_ws, size_t ws_size,
                              hipStream_t stream) {
    (void)in_sizes; (void)n_in; (void)out_size; (void)ws_size;
    const float* seed    = (const float*)d_in[0];
    const float* w_cand  = (const float*)d_in[1];
    const float* novelty = (const float*)d_in[2];
    const float* g_em    = (const float*)d_in[3];
    const float* emK     = (const float*)d_in[4];
    const float* emV     = (const float*)d_in[5];
    const float* emS     = (const float*)d_in[6];
    const float* emAge   = (const float*)d_in[7];
    const float* w1      = (const float*)d_in[8];
    const float* w2      = (const float*)d_in[9];
    const float* gb      = (const float*)d_in[10];
    const float* rt      = (const float*)d_in[11];
    const float* rtw     = (const float*)d_in[12];
    const int*   bp      = (const int*)d_in[13];

    float* out  = (float*)d_out;
    float* yem  = out;
    float* outK = out + 1048576;
    float* outV = out + 3145728;
    float* outS = out + 5242880;
    float* outA = out + 5259264;

    us_t* Kbf = (us_t*)d_ws;                               // [8][2048][128]
    us_t* Wcg = Kbf + (size_t)BS_ * M_ * D_;               // [8][1024][128]
    us_t* WcT = Wcg + (size_t)BS_ * N_ * D_;               // [8][128][1024]
    us_t* Vtg = WcT + (size_t)BS_ * D_ * N_;               // [8][128][2048]
    us_t* pDelta = Vtg + (size_t)BS_ * D_ * M_;            // [512][64][128]
    float* fb    = (float*)(pDelta + (size_t)512 * 64 * 128);
    float* invnW = fb;                                     // 8192
    float* mxW   = invnW + BS_ * N_;                       // 32768
    float* smW   = mxW + 4 * BS_ * N_;                     // 32768
    float* mxF   = smW + 4 * BS_ * N_;                     // 8192
    float* rivF  = mxF + BS_ * N_;                         // 8192
    float* punF  = rivF + BS_ * N_;                        // 8192
    float* y1    = punF + BS_ * N_;                        // 1,048,576
    float2* pML  = (float2*)(y1 + (size_t)BS_ * N_ * D_);  // 32768 float2

    conv_k<<<dim3(80, 8), 256, 0, stream>>>(w_cand, emK, emV, bp, Kbf, Wcg, WcT, Vtg, invnW);

    attn_part_k<<<dim3(512), 256, 0, stream>>>(seed, Kbf, Vtg, emS, rt, bp, pDelta, pML);
    attn_merge_k<<<dim3(128), 256, 0, stream>>>(seed, seed, pDelta, pML, w1, w2, gb, bp, y1, 0);
    attn_part_k<<<dim3(512), 256, 0, stream>>>(y1, Kbf, Vtg, emS, rt, bp, pDelta, pML);
    attn_merge_k<<<dim3(128), 256, 0, stream>>>(y1, seed, pDelta, pML, w1, w2, gb, bp, yem, 1);

    stats_k<<<dim3(512), 256, 0, stream>>>(Wcg, Kbf, invnW, emS, rtw, bp, mxW, smW);
    stats_fin_k<<<dim3(32), 256, 0, stream>>>(mxW, smW, novelty, mxF, rivF, punF);
    update4_k<<<dim3(512), 256, 0, stream>>>(Kbf, Wcg, WcT, g_em, emK, emV, emS, emAge,
                                             rtw, bp, invnW, mxF, rivF, punF,
                                             outK, outV, outS, outA);
    scale_s_k<<<8, 256, 0, stream>>>(outS);
}

// Round 8
// 293.078 us; speedup vs baseline: 1.3701x; 1.0036x over previous
//
#include <hip/hip_runtime.h>
#include <hip/hip_bf16.h>
#include <math.h>

#define BS_ 8
#define B_  4
#define M_  2048
#define D_  128
#define N_  1024
#define NEG (-1e30f)

typedef unsigned short us_t;
typedef __attribute__((ext_vector_type(8))) short bf8v;   // 8 bf16 (A/B frag)
typedef __attribute__((ext_vector_type(4))) float f4v;    // C/D frag

__device__ __forceinline__ float softplus_(float x) {
    return (x > 20.0f) ? x : log1pf(expf(x));
}
__device__ __forceinline__ float dot4_acc(float4 a, float4 b, float acc) {
    acc = fmaf(a.x, b.x, acc);
    acc = fmaf(a.y, b.y, acc);
    acc = fmaf(a.z, b.z, acc);
    acc = fmaf(a.w, b.w, acc);
    return acc;
}
__device__ __forceinline__ us_t f2bf(float x) {
    __hip_bfloat16 h = __float2bfloat16(x);   // RNE
    return __builtin_bit_cast(us_t, h);
}
__device__ __forceinline__ float bf2f(us_t u) {
    unsigned v = ((unsigned)u) << 16;
    return __builtin_bit_cast(float, v);
}
__device__ __forceinline__ bf8v gfrag(const us_t* p) { return *(const bf8v*)p; }  // 16B L2 load
// LDS swizzle: XOR bits 3-5 of ushort index with row&7
__device__ __forceinline__ int swz(int us_idx, int row) { return us_idx ^ ((row & 7) << 3); }

// ---------------------------------------------------------------------------
// conv_k: f32 -> bf16 conversions into ws (round-4 proven).
// ---------------------------------------------------------------------------
__global__ __launch_bounds__(256, 2) void conv_k(
    const float* __restrict__ w_cand, const float* __restrict__ emK,
    const float* __restrict__ emV, const int* __restrict__ bp,
    us_t* __restrict__ Kbf, us_t* __restrict__ Wcg,
    us_t* __restrict__ WcTg, us_t* __restrict__ Vtg, float* __restrict__ invnW)
{
    __shared__ float wt[64][132];
    __shared__ float invn[64];
    const int tid = threadIdx.x;
    const int bs  = blockIdx.y;
    const int bx  = blockIdx.x;
    const int b   = bp[0];

    if (bx < 32) {
        const float* src = emK + ((size_t)(bs * B_ + b)) * M_ * D_ + (size_t)bx * 64 * D_;
        us_t* dst = Kbf + (size_t)bs * M_ * D_ + (size_t)bx * 64 * D_;
        for (int i = tid; i < 64 * 128 / 4; i += 256) {
            float4 v = ((const float4*)src)[i];
            ushort4 o;
            o.x = f2bf(v.x); o.y = f2bf(v.y); o.z = f2bf(v.z); o.w = f2bf(v.w);
            ((ushort4*)dst)[i] = o;
        }
        return;
    }
    if (bx >= 48) {
        const int m0 = (bx - 48) * 64;
        const float* Vb = emV + ((size_t)(bs * B_ + b)) * M_ * D_ + (size_t)m0 * D_;
        for (int c = tid; c < 64 * 32; c += 256) {
            int row = c >> 5, col = (c & 31) << 2;
            *(float4*)&wt[row][col] = *(const float4*)&Vb[row * D_ + col];
        }
        __syncthreads();
        us_t* VtB = Vtg + (size_t)bs * D_ * M_;
        for (int c = tid; c < 1024; c += 256) {
            int d = c >> 3, mc = c & 7;
            uint4 o;
            o.x = (unsigned)f2bf(wt[mc * 8 + 0][d]) | ((unsigned)f2bf(wt[mc * 8 + 1][d]) << 16);
            o.y = (unsigned)f2bf(wt[mc * 8 + 2][d]) | ((unsigned)f2bf(wt[mc * 8 + 3][d]) << 16);
            o.z = (unsigned)f2bf(wt[mc * 8 + 4][d]) | ((unsigned)f2bf(wt[mc * 8 + 5][d]) << 16);
            o.w = (unsigned)f2bf(wt[mc * 8 + 6][d]) | ((unsigned)f2bf(wt[mc * 8 + 7][d]) << 16);
            *(uint4*)&VtB[(size_t)d * M_ + m0 + mc * 8] = o;
        }
        return;
    }
    const int n0 = (bx - 32) * 64;
    const float* Wb = w_cand + (size_t)bs * N_ * D_ + (size_t)n0 * D_;
    for (int c = tid; c < 64 * 32; c += 256) {
        int row = c >> 5, col = (c & 31) << 2;
        *(float4*)&wt[row][col] = *(const float4*)&Wb[row * D_ + col];
    }
    __syncthreads();
    {
        int r = tid >> 2, j = tid & 3;
        float ss = 0.0f;
        #pragma unroll
        for (int q = 0; q < 8; ++q) {
            float4 v = *(float4*)&wt[r][q * 16 + j * 4];
            ss = dot4_acc(v, v, ss);
        }
        ss += __shfl_xor(ss, 1, 4);
        ss += __shfl_xor(ss, 2, 4);
        if (j == 0) invn[r] = 1.0f / fmaxf(sqrtf(ss), 1e-12f);
    }
    __syncthreads();
    us_t* WcB = Wcg + (size_t)bs * N_ * D_ + (size_t)n0 * D_;
    for (int e = tid; e < 8192; e += 256) {
        int row = e >> 7, col = e & 127;
        WcB[row * D_ + col] = f2bf(wt[row][col]);
    }
    us_t* WcTB = WcTg + (size_t)bs * D_ * N_;
    for (int e = tid; e < 8192; e += 256) {
        int d = e >> 6, n = e & 63;
        WcTB[d * N_ + n0 + n] = f2bf(wt[n][d]);
    }
    if (tid < 64) invnW[(size_t)bs * N_ + n0 + tid] = invn[tid];
}

// ---------------------------------------------------------------------------
// attn_part_k: flash-attention partial over one M-quarter (round-4 proven:
// double-buffered LDS staging). 512 blocks, 4 waves x 16 n-rows.
// ---------------------------------------------------------------------------
__global__ __launch_bounds__(256, 2) void attn_part_k(
    const float* __restrict__ ySrc, const us_t* __restrict__ Kbf,
    const us_t* __restrict__ Vtg, const float* __restrict__ emS,
    const float* __restrict__ raw_tau, const int* __restrict__ bp,
    us_t* __restrict__ pDelta, float2* __restrict__ pML)
{
    __shared__ us_t KtL[2][8192];
    __shared__ us_t VtL[2][8192];
    __shared__ us_t Pl[4][1024];
    __shared__ float sbt[2][64];

    const int tid = threadIdx.x;
    const int raw = blockIdx.x;
    const int logical = (raw & 7) * 64 + (raw >> 3);   // 512 = 8 XCD * 64
    const int bs = logical >> 6;
    const int rem = logical & 63;
    const int nt = rem >> 2;
    const int q  = rem & 3;
    const int b = bp[0];
    const float rtau = 1.0f / (softplus_(raw_tau[b]) + 0.1f);

    const us_t* KbB = Kbf + (size_t)bs * M_ * D_ + (size_t)(q * 512) * D_;
    const us_t* VtB = Vtg + (size_t)bs * D_ * M_;
    const float* SbB = emS + ((size_t)(bs * B_ + b)) * M_ + q * 512;

    const int wave = tid >> 6, lane = tid & 63;
    const int r = lane & 15, kg = lane >> 4;

    bf8v yb[4];
    {
        const float* yrow = ySrc + ((size_t)bs * N_ + nt * 64 + wave * 16 + r) * D_;
        #pragma unroll
        for (int kk = 0; kk < 4; ++kk) {
            float4 a = *(const float4*)&yrow[kk * 32 + kg * 8];
            float4 c = *(const float4*)&yrow[kk * 32 + kg * 8 + 4];
            bf8v t;
            t[0] = (short)f2bf(a.x); t[1] = (short)f2bf(a.y);
            t[2] = (short)f2bf(a.z); t[3] = (short)f2bf(a.w);
            t[4] = (short)f2bf(c.x); t[5] = (short)f2bf(c.y);
            t[6] = (short)f2bf(c.z); t[7] = (short)f2bf(c.w);
            yb[kk] = t;
        }
    }

    uint4 kr[4], vr[4];
    float sreg = 0.0f;

#define AP_LOAD(t) do {                                                           \
        for (int i = 0; i < 4; ++i) {                                             \
            int c = tid + i * 256;                                                \
            kr[i] = *(const uint4*)&KbB[(size_t)((t) * 64 + (c >> 4)) * D_ + ((c & 15) << 3)]; \
            vr[i] = *(const uint4*)&VtB[(size_t)(c >> 3) * M_ + q * 512 + (t) * 64 + ((c & 7) << 3)]; \
        }                                                                         \
        if (tid < 64) sreg = SbB[(t) * 64 + tid];                                 \
    } while (0)

#define AP_WRITE(bf) do {                                                         \
        for (int i = 0; i < 4; ++i) {                                             \
            int c = tid + i * 256;                                                \
            int ki = (c >> 4) * 128 + ((c & 15) << 3);                            \
            *(uint4*)&KtL[bf][swz(ki, c >> 4)] = kr[i];                           \
            int vi = (c >> 3) * 64 + ((c & 7) << 3);                              \
            *(uint4*)&VtL[bf][swz(vi, c >> 3)] = vr[i];                           \
        }                                                                         \
        if (tid < 64) sbt[bf][tid] = sreg;                                        \
    } while (0)

    f4v cD[8];
    #pragma unroll
    for (int df = 0; df < 8; ++df) cD[df] = (f4v){0.f, 0.f, 0.f, 0.f};
    float mrun = NEG, lsum = 0.0f;

    AP_LOAD(0);
    AP_WRITE(0);
    __syncthreads();

    for (int t = 0; t < 8; ++t) {
        const int cur = t & 1;
        if (t < 7) AP_LOAD(t + 1);

        float sv[4][4];
        #pragma unroll
        for (int mf = 0; mf < 4; ++mf) {
            f4v c4 = {0.f, 0.f, 0.f, 0.f};
            #pragma unroll
            for (int kk = 0; kk < 4; ++kk) {
                int row_ = mf * 16 + r;
                bf8v a = *(bf8v*)&KtL[cur][swz(row_ * 128 + kk * 32 + kg * 8, row_)];
                c4 = __builtin_amdgcn_mfma_f32_16x16x32_bf16(a, yb[kk], c4, 0, 0, 0);
            }
            #pragma unroll
            for (int reg = 0; reg < 4; ++reg) {
                int ml = mf * 16 + kg * 4 + reg;
                sv[mf][reg] = (sbt[cur][ml] > 0.0f) ? c4[reg] * rtau : NEG;
            }
        }
        float tmax = NEG;
        #pragma unroll
        for (int mf = 0; mf < 4; ++mf)
            #pragma unroll
            for (int reg = 0; reg < 4; ++reg) tmax = fmaxf(tmax, sv[mf][reg]);
        tmax = fmaxf(tmax, __shfl_xor(tmax, 16, 64));
        tmax = fmaxf(tmax, __shfl_xor(tmax, 32, 64));
        float mnew = fmaxf(mrun, tmax);
        float f = (mnew > -1e29f) ? __expf(mrun - mnew) : 1.0f;
        mrun = mnew;

        float psum = 0.0f;
        #pragma unroll
        for (int mf = 0; mf < 4; ++mf)
            #pragma unroll
            for (int reg = 0; reg < 4; ++reg) {
                float p = (sv[mf][reg] > -1e29f) ? __expf(sv[mf][reg] - mnew) : 0.0f;
                psum += p;
                int ml = mf * 16 + kg * 4 + reg;
                Pl[wave][swz(r * 64 + ml, r)] = f2bf(p);
            }
        lsum = lsum * f + psum;

        float fr[4];
        #pragma unroll
        for (int reg = 0; reg < 4; ++reg) fr[reg] = __shfl(f, kg * 4 + reg, 64);
        #pragma unroll
        for (int df = 0; df < 8; ++df)
            #pragma unroll
            for (int reg = 0; reg < 4; ++reg) cD[df][reg] *= fr[reg];

        #pragma unroll
        for (int kk = 0; kk < 2; ++kk) {
            bf8v pa = *(bf8v*)&Pl[wave][swz(r * 64 + kk * 32 + kg * 8, r)];
            #pragma unroll
            for (int df = 0; df < 8; ++df) {
                int row_ = df * 16 + r;
                bf8v bv = *(bf8v*)&VtL[cur][swz(row_ * 64 + kk * 32 + kg * 8, row_)];
                cD[df] = __builtin_amdgcn_mfma_f32_16x16x32_bf16(pa, bv, cD[df], 0, 0, 0);
            }
        }

        if (t < 7) AP_WRITE(cur ^ 1);
        __syncthreads();
    }
#undef AP_LOAD
#undef AP_WRITE

    lsum += __shfl_xor(lsum, 16, 64);
    lsum += __shfl_xor(lsum, 32, 64);
    float invl = (lsum > 0.0f) ? 1.0f / lsum : 0.0f;

    us_t* pd = pDelta + ((size_t)((bs * 16 + nt) * 4 + q)) * (64 * 128);
    #pragma unroll
    for (int reg = 0; reg < 4; ++reg) {
        float il = __shfl(invl, kg * 4 + reg, 64);
        int nrow = wave * 16 + kg * 4 + reg;
        #pragma unroll
        for (int df = 0; df < 8; ++df)
            pd[nrow * 128 + df * 16 + r] = f2bf(cD[df][reg] * il);
    }
    if (kg == 0) {
        int nrow = wave * 16 + r;
        pML[((size_t)((bs * 16 + nt) * 4 + q)) * 64 + nrow] = make_float2(mrun, lsum);
    }
}

// ---------------------------------------------------------------------------
// attn_merge_k: merge 4 quarters, gate, update y (round-4 proven).
// ---------------------------------------------------------------------------
__global__ __launch_bounds__(256, 2) void attn_merge_k(
    const float* __restrict__ ySrc, const float* __restrict__ seed,
    const us_t* __restrict__ pDelta, const float2* __restrict__ pML,
    const float* __restrict__ w1, const float* __restrict__ w2,
    const float* __restrict__ gb, const int* __restrict__ bp,
    float* __restrict__ yOut, int mode)
{
    __shared__ float w1L[128], w2L[128], gbL[128];
    const int tid = threadIdx.x, raw = blockIdx.x;
    const int logical = (raw & 7) * 16 + (raw >> 3);
    const int bs = logical >> 4, nt = logical & 15;
    const int b = bp[0];
    if (tid < 128) {
        w1L[tid] = w1[b * D_ + tid];
        w2L[tid] = w2[b * D_ + tid];
        gbL[tid] = gb[b * D_ + tid];
    }
    __syncthreads();
    const int rw = tid >> 2, dj = tid & 3;
    const size_t base = ((size_t)(bs * 16 + nt)) * 4;
    float2 ml0 = pML[(base + 0) * 64 + rw];
    float2 ml1 = pML[(base + 1) * 64 + rw];
    float2 ml2 = pML[(base + 2) * 64 + rw];
    float2 ml3 = pML[(base + 3) * 64 + rw];
    float M = fmaxf(fmaxf(ml0.x, ml1.x), fmaxf(ml2.x, ml3.x));
    float w0 = 0.f, wA = 0.f, wB = 0.f, w3 = 0.f, tot = 0.f;
    if (M > -1e29f) {
        w0 = ml0.y * __expf(ml0.x - M);
        wA = ml1.y * __expf(ml1.x - M);
        wB = ml2.y * __expf(ml2.x - M);
        w3 = ml3.y * __expf(ml3.x - M);
        tot = w0 + wA + wB + w3;
    }
    float inv = (tot > 0.0f) ? 1.0f / tot : 0.0f;
    w0 *= inv; wA *= inv; wB *= inv; w3 *= inv;

    const us_t* pd0 = pDelta + (base + 0) * 8192 + rw * 128;
    const us_t* pd1 = pDelta + (base + 1) * 8192 + rw * 128;
    const us_t* pd2 = pDelta + (base + 2) * 8192 + rw * 128;
    const us_t* pd3 = pDelta + (base + 3) * 8192 + rw * 128;
    const float* yrow = ySrc + ((size_t)bs * N_ + nt * 64 + rw) * D_;
    const float* srow = seed + ((size_t)bs * N_ + nt * 64 + rw) * D_;
    float* orow = yOut + ((size_t)bs * N_ + nt * 64 + rw) * D_;

    #pragma unroll
    for (int e = 0; e < 4; ++e) {
        int d0 = dj * 32 + e * 8;
        uint4 u0 = *(const uint4*)&pd0[d0];
        uint4 u1 = *(const uint4*)&pd1[d0];
        uint4 u2 = *(const uint4*)&pd2[d0];
        uint4 u3 = *(const uint4*)&pd3[d0];
        const us_t* a0 = (const us_t*)&u0;
        const us_t* a1 = (const us_t*)&u1;
        const us_t* a2 = (const us_t*)&u2;
        const us_t* a3 = (const us_t*)&u3;
        float4 ya = *(const float4*)&yrow[d0];
        float4 yc = *(const float4*)&yrow[d0 + 4];
        float yv[8] = {ya.x, ya.y, ya.z, ya.w, yc.x, yc.y, yc.z, yc.w};
        float res[8];
        #pragma unroll
        for (int j = 0; j < 8; ++j) {
            float dl = w0 * bf2f(a0[j]) + wA * bf2f(a1[j]) + wB * bf2f(a2[j]) + w3 * bf2f(a3[j]);
            int d = d0 + j;
            float g = 1.0f / (1.0f + __expf(-(w1L[d] * yv[j] + w2L[d] * dl + gbL[d])));
            res[j] = yv[j] + g * dl;
        }
        if (mode == 1) {
            float4 sa = *(const float4*)&srow[d0];
            float4 sc = *(const float4*)&srow[d0 + 4];
            res[0] -= sa.x; res[1] -= sa.y; res[2] -= sa.z; res[3] -= sa.w;
            res[4] -= sc.x; res[5] -= sc.y; res[6] -= sc.z; res[7] -= sc.w;
        }
        float4 o1; o1.x = res[0]; o1.y = res[1]; o1.z = res[2]; o1.w = res[3];
        float4 o2; o2.x = res[4]; o2.y = res[5]; o2.z = res[6]; o2.w = res[7];
        *(float4*)&orow[d0] = o1;
        *(float4*)&orow[d0 + 4] = o2;
    }
}

// ---------------------------------------------------------------------------
// stats_k: routing score stats over one M-quarter (round-4 proven, dbuf).
// ---------------------------------------------------------------------------
__global__ __launch_bounds__(256, 2) void stats_k(
    const us_t* __restrict__ Wcg, const us_t* __restrict__ Kbf,
    const float* __restrict__ invnW, const float* __restrict__ emS,
    const float* __restrict__ raw_tau_w, const int* __restrict__ bp,
    float* __restrict__ mxW, float* __restrict__ smW)
{
    __shared__ us_t KtL[2][8192];
    __shared__ float sbt[2][64];

    const int tid = threadIdx.x;
    const int raw = blockIdx.x;
    const int logical = (raw & 7) * 64 + (raw >> 3);
    const int bs = logical >> 6;
    const int rem = logical & 63;
    const int nt = rem >> 2;
    const int q  = rem & 3;
    const int b = bp[0];
    const float rtw = 1.0f / (softplus_(raw_tau_w[b]) + 0.1f);

    const us_t* KbB = Kbf + (size_t)bs * M_ * D_ + (size_t)(q * 512) * D_;
    const float* SbB = emS + ((size_t)(bs * B_ + b)) * M_ + q * 512;

    const int wave = tid >> 6, lane = tid & 63;
    const int r = lane & 15, kg = lane >> 4;
    const int n = nt * 64 + wave * 16 + r;

    bf8v wb[4];
    {
        const us_t* wrow = Wcg + ((size_t)bs * N_ + n) * D_;
        #pragma unroll
        for (int kk = 0; kk < 4; ++kk)
            wb[kk] = gfrag(&wrow[kk * 32 + kg * 8]);
    }
    const float ivn = invnW[(size_t)bs * N_ + n];

    uint4 kr[4];
    float sreg = 0.0f;

#define ST_LOAD(t) do {                                                           \
        for (int i = 0; i < 4; ++i) {                                             \
            int c = tid + i * 256;                                                \
            kr[i] = *(const uint4*)&KbB[(size_t)((t) * 64 + (c >> 4)) * D_ + ((c & 15) << 3)]; \
        }                                                                         \
        if (tid < 64) sreg = SbB[(t) * 64 + tid];                                 \
    } while (0)

#define ST_WRITE(bf) do {                                                         \
        for (int i = 0; i < 4; ++i) {                                             \
            int c = tid + i * 256;                                                \
            int ki = (c >> 4) * 128 + ((c & 15) << 3);                            \
            *(uint4*)&KtL[bf][swz(ki, c >> 4)] = kr[i];                           \
        }                                                                         \
        if (tid < 64) sbt[bf][tid] = sreg;                                        \
    } while (0)

    float mx = NEG, sm = 0.0f;

    ST_LOAD(0);
    ST_WRITE(0);
    __syncthreads();

    for (int t = 0; t < 8; ++t) {
        const int cur = t & 1;
        if (t < 7) ST_LOAD(t + 1);

        #pragma unroll
        for (int mf = 0; mf < 4; ++mf) {
            f4v c4 = {0.f, 0.f, 0.f, 0.f};
            #pragma unroll
            for (int kk = 0; kk < 4; ++kk) {
                int row_ = mf * 16 + r;
                bf8v a = *(bf8v*)&KtL[cur][swz(row_ * 128 + kk * 32 + kg * 8, row_)];
                c4 = __builtin_amdgcn_mfma_f32_16x16x32_bf16(a, wb[kk], c4, 0, 0, 0);
            }
            float v[4]; bool act[4];
            float lm = NEG;
            #pragma unroll
            for (int reg = 0; reg < 4; ++reg) {
                int ml = mf * 16 + kg * 4 + reg;
                v[reg] = c4[reg] * ivn * rtw;
                act[reg] = (sbt[cur][ml] > 0.0f);
                if (act[reg]) lm = fmaxf(lm, v[reg]);
            }
            float mnew = fmaxf(mx, lm);
            if (mnew > -1e29f) {
                float acc = sm * __expf(mx - mnew);
                #pragma unroll
                for (int reg = 0; reg < 4; ++reg)
                    if (act[reg]) acc += __expf(v[reg] - mnew);
                sm = acc; mx = mnew;
            }
        }

        if (t < 7) ST_WRITE(cur ^ 1);
        __syncthreads();
    }
#undef ST_LOAD
#undef ST_WRITE

    #pragma unroll
    for (int off = 16; off <= 32; off <<= 1) {
        float omx = __shfl_xor(mx, off, 64);
        float osm = __shfl_xor(sm, off, 64);
        float nm = fmaxf(mx, omx);
        if (nm > -1e29f) sm = sm * __expf(mx - nm) + osm * __expf(omx - nm);
        else sm = 0.0f;
        mx = nm;
    }
    if (kg == 0) {
        mxW[(size_t)(q * BS_ + bs) * N_ + n] = mx;
        smW[(size_t)(q * BS_ + bs) * N_ + n] = sm;
    }
}

// ---------------------------------------------------------------------------
// stats_fin_k: merge 4 quarters -> per-n softmax constants (round-4 proven).
// ---------------------------------------------------------------------------
__global__ __launch_bounds__(256) void stats_fin_k(
    const float* __restrict__ mxW, const float* __restrict__ smW,
    const float* __restrict__ novelty,
    float* __restrict__ mxF, float* __restrict__ rivF, float* __restrict__ punF)
{
    int idx = blockIdx.x * 256 + threadIdx.x;   // 32 blocks * 256 = 8192
    float m[4], s[4];
    #pragma unroll
    for (int q = 0; q < 4; ++q) {
        m[q] = mxW[q * (BS_ * N_) + idx];
        s[q] = smW[q * (BS_ * N_) + idx];
    }
    float MX = fmaxf(fmaxf(m[0], m[1]), fmaxf(m[2], m[3]));
    float SM = 0.0f;
    if (MX > -1e29f) {
        #pragma unroll
        for (int q = 0; q < 4; ++q)
            if (m[q] > -1e29f) SM += s[q] * __expf(m[q] - MX);
    }
    float nov = novelty[idx];
    if (SM > 0.0f) { mxF[idx] = MX; rivF[idx] = nov / SM; punF[idx] = -1.0f; }
    else           { mxF[idx] = 0.0f; rivF[idx] = 0.0f; punF[idx] = nov * (1.0f / (float)M_); }
}

// ---------------------------------------------------------------------------
// update5_k: update4 structure + (a) __launch_bounds__(256,2) so the
// allocator has a 256-VGPR budget (round-7's 112-reg allocation spilled
// accumulators -> 87MB scratch write traffic), (b) LDS-staged coalesced
// epilogue (float4 blend I/O instead of stride-64B scatter).
// ---------------------------------------------------------------------------
__global__ __launch_bounds__(256, 2) void update5_k(
    const us_t* __restrict__ Kbf, const us_t* __restrict__ Wcg,
    const us_t* __restrict__ WcTg, const float* __restrict__ g_em,
    const float* __restrict__ emK, const float* __restrict__ emV,
    const float* __restrict__ emS, const float* __restrict__ emAge,
    const float* __restrict__ raw_tau_w, const int* __restrict__ bp,
    const float* __restrict__ invnW, const float* __restrict__ mxF,
    const float* __restrict__ rivF, const float* __restrict__ punF,
    float* __restrict__ outK, float* __restrict__ outV,
    float* __restrict__ outS, float* __restrict__ outA)
{
    __shared__ __align__(16) char smraw[32768];   // staging; reused for merge + epilogue
    us_t* WcS  = (us_t*)smraw;             // [64n][128d]
    us_t* WcTS = (us_t*)(smraw + 16384);   // [128d][64n]
    __shared__ us_t Pl[2][1024];           // per-mf P tiles [16m][64n]
    __shared__ us_t P2l[2][1024];
    __shared__ float4 cns[64];
    __shared__ float4 pcs[2][64];
    __shared__ float aL[32];

    const int tid = threadIdx.x;
    const int raw = blockIdx.x;
    const int logical = (raw & 7) * 64 + (raw >> 3);   // 512 = 8 XCD * 64
    const int bs = logical >> 6;
    const int m0 = (logical & 63) * 32;
    const int b = bp[0];
    const float rtw = 1.0f / (softplus_(raw_tau_w[b]) + 0.1f);
    const float ge = g_em[bs];

    const int wave = tid >> 6, lane = tid & 63;
    const int mf = wave & 1, nfh = wave >> 1;
    const int r = lane & 15, kg = lane >> 4;
    const int mrow0 = m0 + mf * 16;

    const us_t* WcB  = Wcg + (size_t)bs * N_ * D_;
    const us_t* WcTB = WcTg + (size_t)bs * D_ * N_;
    const float* SbRow = emS + ((size_t)(bs * B_ + b)) * M_ + mrow0;

    // A fragments (K rows), loaded once (L2-direct is fine for one-shot loads)
    bf8v a_s[4];
    {
        const us_t* arow = Kbf + ((size_t)bs * M_ + mrow0 + r) * D_;
        #pragma unroll
        for (int kk = 0; kk < 4; ++kk)
            a_s[kk] = gfrag(&arow[kk * 32 + kg * 8]);
    }
    bool act4[4];
    #pragma unroll
    for (int reg = 0; reg < 4; ++reg) act4[reg] = (SbRow[kg * 4 + reg] > 0.0f);

    f4v cK[8], cV[8];
    #pragma unroll
    for (int df = 0; df < 8; ++df) { cK[df] = (f4v){0,0,0,0}; cV[df] = (f4v){0,0,0,0}; }
    float csp[4] = {0.f, 0.f, 0.f, 0.f};

    uint4 wr[4], wtr[4];
    float4 creg = {0.f, 0.f, 0.f, 0.f};

#define U5_LOAD(t) do {                                                            \
        for (int i = 0; i < 4; ++i) {                                              \
            int c = tid + i * 256;                                                 \
            wr[i]  = *(const uint4*)&WcB[((size_t)((t) * 64 + (c >> 4))) * D_ + ((c & 15) << 3)]; \
            wtr[i] = *(const uint4*)&WcTB[((size_t)(c >> 3)) * N_ + (t) * 64 + ((c & 7) << 3)];   \
        }                                                                          \
        if (tid < 64) {                                                            \
            int nn = (t) * 64 + tid;                                               \
            creg.x = mxF[(size_t)bs * N_ + nn];                                    \
            creg.y = rivF[(size_t)bs * N_ + nn];                                   \
            creg.z = punF[(size_t)bs * N_ + nn];                                   \
            creg.w = invnW[(size_t)bs * N_ + nn];                                  \
        }                                                                          \
    } while (0)

#define U5_WRITE() do {                                                            \
        for (int i = 0; i < 4; ++i) {                                              \
            int c = tid + i * 256;                                                 \
            int ki = (c >> 4) * 128 + ((c & 15) << 3);                             \
            *(uint4*)&WcS[swz(ki, c >> 4)] = wr[i];                                \
            int vi = (c >> 3) * 64 + ((c & 7) << 3);                               \
            *(uint4*)&WcTS[swz(vi, c >> 3)] = wtr[i];                              \
        }                                                                          \
        if (tid < 64) cns[tid] = creg;                                             \
    } while (0)

    U5_LOAD(0);
    U5_WRITE();
    U5_LOAD(1);
    __syncthreads();

    for (int nt = 0; nt < 16; ++nt) {
        // scores + P/P2 for this wave's two 16-col groups (cols nfh*32..+31)
        #pragma unroll
        for (int nf2 = 0; nf2 < 2; ++nf2) {
            const int nf = nfh * 2 + nf2;
            f4v c = {0.f, 0.f, 0.f, 0.f};
            #pragma unroll
            for (int kk = 0; kk < 4; ++kk) {
                int row = nf * 16 + r;
                bf8v bb = *(bf8v*)&WcS[swz(row * 128 + kk * 32 + kg * 8, row)];
                c = __builtin_amdgcn_mfma_f32_16x16x32_bf16(a_s[kk], bb, c, 0, 0, 0);
            }
            int nl = nf * 16 + r;
            float4 cn = cns[nl];
            #pragma unroll
            for (int reg = 0; reg < 4; ++reg) {
                float p;
                if (cn.z >= 0.0f) p = cn.z;
                else p = act4[reg] ? cn.y * __expf(c[reg] * cn.w * rtw - cn.x) : 0.0f;
                csp[reg] += p;
                int mr = kg * 4 + reg;
                Pl[mf][swz(mr * 64 + nl, mr)] = f2bf(p);
                P2l[mf][swz(mr * 64 + nl, mr)] = f2bf(p * cn.w);
            }
        }
        // update GEMMs: this wave covers k-slot nfh (cols it just wrote)
        {
            bf8v pa  = *(bf8v*)&Pl[mf][swz(r * 64 + nfh * 32 + kg * 8, r)];
            bf8v pa2 = *(bf8v*)&P2l[mf][swz(r * 64 + nfh * 32 + kg * 8, r)];
            #pragma unroll
            for (int df = 0; df < 8; ++df) {
                int row = df * 16 + r;
                bf8v bw = *(bf8v*)&WcTS[swz(row * 64 + nfh * 32 + kg * 8, row)];
                cV[df] = __builtin_amdgcn_mfma_f32_16x16x32_bf16(pa, bw, cV[df], 0, 0, 0);
                cK[df] = __builtin_amdgcn_mfma_f32_16x16x32_bf16(pa2, bw, cK[df], 0, 0, 0);
            }
        }
        if (nt < 15) {
            __syncthreads();            // everyone done reading stage
            U5_WRITE();                 // waits on prefetch regs (vmcnt)
            if (nt + 2 < 16) U5_LOAD(nt + 2);
            __syncthreads();            // stage ready
        }
    }
#undef U5_LOAD
#undef U5_WRITE

    // ---- merge the two column-halves (reuse staging LDS) ----
    __syncthreads();
    f4v* pK = (f4v*)smraw;              // [2][8][64]
    f4v* pV = (f4v*)(smraw + 16384);
    if (nfh == 1) {
        #pragma unroll
        for (int df = 0; df < 8; ++df) {
            pK[(mf * 8 + df) * 64 + lane] = cK[df];
            pV[(mf * 8 + df) * 64 + lane] = cV[df];
        }
        pcs[mf][lane] = make_float4(csp[0], csp[1], csp[2], csp[3]);
    }
    __syncthreads();

    if (nfh == 0) {
        #pragma unroll
        for (int df = 0; df < 8; ++df) {
            cK[df] += pK[(mf * 8 + df) * 64 + lane];
            cV[df] += pV[(mf * 8 + df) * 64 + lane];
        }
        float4 pc = pcs[mf][lane];
        csp[0] += pc.x; csp[1] += pc.y; csp[2] += pc.z; csp[3] += pc.w;
    }
    __syncthreads();   // pK/pV reads done; smraw may be reused below

    float* KoutL = (float*)smraw;              // [32][128] f32
    float* VoutL = (float*)(smraw + 16384);    // [32][128] f32

    if (nfh == 0) {
        // cs reduce over the 16 column-lanes
        #pragma unroll
        for (int reg = 0; reg < 4; ++reg) {
            float v = csp[reg];
            v += __shfl_xor(v, 1, 16);
            v += __shfl_xor(v, 2, 16);
            v += __shfl_xor(v, 4, 16);
            v += __shfl_xor(v, 8, 16);
            csp[reg] = v;   // cs for row kg*4+reg
        }

        float rden[4], nrm[4], alpha4[4];
        #pragma unroll
        for (int reg = 0; reg < 4; ++reg) {
            float csv = csp[reg];
            alpha4[reg] = fminf(ge * csv * (1.0f / (float)N_), 1.0f);
            rden[reg] = 1.0f / fmaxf(csv, 1e-8f);
            float s = 0.0f;
            #pragma unroll
            for (int df = 0; df < 8; ++df) {
                float u = cK[df][reg] * rden[reg];
                s += u * u;
            }
            s += __shfl_xor(s, 1, 16);
            s += __shfl_xor(s, 2, 16);
            s += __shfl_xor(s, 4, 16);
            s += __shfl_xor(s, 8, 16);
            nrm[reg] = 1.0f / fmaxf(sqrtf(s), 1e-12f);
        }

        // stage uK/uV rows (f32) + per-row alpha into LDS
        #pragma unroll
        for (int reg = 0; reg < 4; ++reg) {
            int mrow = mf * 16 + kg * 4 + reg;
            #pragma unroll
            for (int df = 0; df < 8; ++df) {
                KoutL[mrow * 128 + df * 16 + r] = cK[df][reg] * rden[reg] * nrm[reg];
                VoutL[mrow * 128 + df * 16 + r] = cV[df][reg] * rden[reg];
            }
            if (r == 0) aL[mrow] = alpha4[reg];
        }

        // outS / outA for this wave's 16 rows
        float cs0 = __shfl(csp[0], (r >> 2) * 16, 64);
        float cs1 = __shfl(csp[1], (r >> 2) * 16, 64);
        float cs2 = __shfl(csp[2], (r >> 2) * 16, 64);
        float cs3 = __shfl(csp[3], (r >> 2) * 16, 64);
        if (kg == 0) {
            int sel = r & 3;
            float csv = (sel == 0) ? cs0 : (sel == 1) ? cs1 : (sel == 2) ? cs2 : cs3;
            float a = fminf(ge * csv * (1.0f / (float)N_), 1.0f);
            float sb = SbRow[r];
            float sp = fminf(fmaxf(sb + a, 0.0f), 3.0f);
            outS[(size_t)bs * M_ + mrow0 + r] = sp;
            outA[(size_t)bs * M_ + mrow0 + r] =
                emAge[((size_t)(bs * B_ + b)) * M_ + mrow0 + r] * (1.0f - a);
        }
    }
    __syncthreads();

    // ---- coalesced blend + writeout (all 256 threads, float4) ----
    const float* KbT = emK + ((size_t)(bs * B_ + b)) * M_ * D_ + (size_t)m0 * D_;
    const float* VbT = emV + ((size_t)(bs * B_ + b)) * M_ * D_ + (size_t)m0 * D_;
    float* oK = outK + (size_t)bs * M_ * D_ + (size_t)m0 * D_;
    float* oV = outV + (size_t)bs * M_ * D_ + (size_t)m0 * D_;
    for (int i = tid; i < 32 * 32; i += 256) {
        int row = i >> 5, c4 = (i & 31) << 2;
        float a = aL[row];
        float4 kv = *(const float4*)&KbT[row * D_ + c4];
        float4 uk = *(const float4*)&KoutL[row * 128 + c4];
        float4 vv = *(const float4*)&VbT[row * D_ + c4];
        float4 uv = *(const float4*)&VoutL[row * 128 + c4];
        float4 ok, ov;
        ok.x = (1.0f - a) * kv.x + a * uk.x;
        ok.y = (1.0f - a) * kv.y + a * uk.y;
        ok.z = (1.0f - a) * kv.z + a * uk.z;
        ok.w = (1.0f - a) * kv.w + a * uk.w;
        ov.x = (1.0f - a) * vv.x + a * uv.x;
        ov.y = (1.0f - a) * vv.y + a * uv.y;
        ov.z = (1.0f - a) * vv.z + a * uv.z;
        ov.w = (1.0f - a) * vv.w + a * uv.w;
        *(float4*)&oK[row * D_ + c4] = ok;
        *(float4*)&oV[row * D_ + c4] = ov;
    }
}

// ---------------------------------------------------------------------------
__global__ __launch_bounds__(256) void scale_s_k(float* __restrict__ outS)
{
    __shared__ float wsum[4];
    const int bs = blockIdx.x, tid = threadIdx.x;
    float* p = outS + (size_t)bs * M_;
    float s = 0.0f;
    for (int i = tid; i < M_; i += 256) s += p[i];
    #pragma unroll
    for (int o = 32; o >= 1; o >>= 1) s += __shfl_xor(s, o, 64);
    if ((tid & 63) == 0) wsum[tid >> 6] = s;
    __syncthreads();
    float tot = wsum[0] + wsum[1] + wsum[2] + wsum[3];
    float scale = fminf(1.0f, 32.0f / fmaxf(tot, 1e-8f));
    for (int i = tid; i < M_; i += 256) p[i] *= scale;
}

// ---------------------------------------------------------------------------
extern "C" void kernel_launch(void* const* d_in, const int* in_sizes, int n_in,
                              void* d_out, int out_size, void* d_ws, size_t ws_size,
                              hipStream_t stream) {
    (void)in_sizes; (void)n_in; (void)out_size; (void)ws_size;
    const float* seed    = (const float*)d_in[0];
    const float* w_cand  = (const float*)d_in[1];
    const float* novelty = (const float*)d_in[2];
    const float* g_em    = (const float*)d_in[3];
    const float* emK     = (const float*)d_in[4];
    const float* emV     = (const float*)d_in[5];
    const float* emS     = (const float*)d_in[6];
    const float* emAge   = (const float*)d_in[7];
    const float* w1      = (const float*)d_in[8];
    const float* w2      = (const float*)d_in[9];
    const float* gb      = (const float*)d_in[10];
    const float* rt      = (const float*)d_in[11];
    const float* rtw     = (const float*)d_in[12];
    const int*   bp      = (const int*)d_in[13];

    float* out  = (float*)d_out;
    float* yem  = out;
    float* outK = out + 1048576;
    float* outV = out + 3145728;
    float* outS = out + 5242880;
    float* outA = out + 5259264;

    us_t* Kbf = (us_t*)d_ws;                               // [8][2048][128]
    us_t* Wcg = Kbf + (size_t)BS_ * M_ * D_;               // [8][1024][128]
    us_t* WcT = Wcg + (size_t)BS_ * N_ * D_;               // [8][128][1024]
    us_t* Vtg = WcT + (size_t)BS_ * D_ * N_;               // [8][128][2048]
    us_t* pDelta = Vtg + (size_t)BS_ * D_ * M_;            // [512][64][128]
    float* fb    = (float*)(pDelta + (size_t)512 * 64 * 128);
    float* invnW = fb;                                     // 8192
    float* mxW   = invnW + BS_ * N_;                       // 32768
    float* smW   = mxW + 4 * BS_ * N_;                     // 32768
    float* mxF   = smW + 4 * BS_ * N_;                     // 8192
    float* rivF  = mxF + BS_ * N_;                         // 8192
    float* punF  = rivF + BS_ * N_;                        // 8192
    float* y1    = punF + BS_ * N_;                        // 1,048,576
    float2* pML  = (float2*)(y1 + (size_t)BS_ * N_ * D_);  // 32768 float2

    conv_k<<<dim3(80, 8), 256, 0, stream>>>(w_cand, emK, emV, bp, Kbf, Wcg, WcT, Vtg, invnW);

    attn_part_k<<<dim3(512), 256, 0, stream>>>(seed, Kbf, Vtg, emS, rt, bp, pDelta, pML);
    attn_merge_k<<<dim3(128), 256, 0, stream>>>(seed, seed, pDelta, pML, w1, w2, gb, bp, y1, 0);
    attn_part_k<<<dim3(512), 256, 0, stream>>>(y1, Kbf, Vtg, emS, rt, bp, pDelta, pML);
    attn_merge_k<<<dim3(128), 256, 0, stream>>>(y1, seed, pDelta, pML, w1, w2, gb, bp, yem, 1);

    stats_k<<<dim3(512), 256, 0, stream>>>(Wcg, Kbf, invnW, emS, rtw, bp, mxW, smW);
    stats_fin_k<<<dim3(32), 256, 0, stream>>>(mxW, smW, novelty, mxF, rivF, punF);
    update5_k<<<dim3(512), 256, 0, stream>>>(Kbf, Wcg, WcT, g_em, emK, emV, emS, emAge,
                                             rtw, bp, invnW, mxF, rivF, punF,
                                             outK, outV, outS, outA);
    scale_s_k<<<8, 256, 0, stream>>>(outS);
}